// Round 1
// baseline (2405.513 us; speedup 1.0000x reference)
//
#include <hip/hip_runtime.h>
#include <math.h>

#define NB 128
#define NT 8
#define NJ 22
#define NF 128
#define NH 8
#define NDH 64
#define NS 66     // 3*NJ
#define NW 6      // NT-2
#define NOUT 512
#define NHD 512   // NH*NDH
#define NEGV -9e15f

// ---------------------------------------------------------------------------
// Kernel A: fused  (x + PE) -> window -> QKV -> masked/thresholded attention
//           -> PV -> Wcls  for one (batch, window, head).
// Writes pre-ft activation [B, W*J, H*DH] directly into d_out.
// grid = B*W*H = 6144 blocks, 256 threads (4 waves).
// ---------------------------------------------------------------------------
__global__ __launch_bounds__(256) void attn_kernel(
    const float* __restrict__ x,
    const float* __restrict__ Wq, const float* __restrict__ bq,
    const float* __restrict__ Wk, const float* __restrict__ bk,
    const float* __restrict__ Wv, const float* __restrict__ bv,
    const float* __restrict__ Wcls, const float* __restrict__ bcls,
    float* __restrict__ out)
{
    __shared__ float s_xw[NS][33];      // f-chunk of the 66x128 window (+pad)
    __shared__ float s_q [NS][NDH];     // q/8 ; later reused for attention out
    __shared__ float s_kT[NDH][NS];     // k transposed: kT[d][s]
    __shared__ float s_v [NS][NDH];     // relu(v)

    const int tid  = threadIdx.x;
    const int lane = tid & 63;
    const int wv   = tid >> 6;          // wave id 0..3
    const int bid  = blockIdx.x;
    const int h = bid & 7;
    const int w = (bid >> 3) % NW;
    const int b = bid / (NH * NW);

    const int col = h * NDH + lane;     // column in the H*DH projection

    // register accumulators: wave wv owns rows s = wv + 4*u  (u < 17)
    float acc0[17], acc1[17], acc2[17];
    const float bqv = bq[col], bkv = bk[col], bvv = bv[col];
#pragma unroll
    for (int u = 0; u < 17; ++u) { acc0[u] = bqv; acc1[u] = bkv; acc2[u] = bvv; }

    const float cdiv = -0.0719557841560639f;  // -ln(10000)/128

    for (int fc = 0; fc < NF; fc += 32) {
        __syncthreads();   // previous chunk fully consumed
        // stage x + Spe + Tpe for this f-chunk
        for (int idx = tid; idx < NS * 32; idx += 256) {
            int s = idx >> 5;
            int u = idx & 31;
            int i = s / NJ;
            int j = s - i * NJ;
            int fr = w + i;             // absolute frame index
            int f = fc + u;
            float xv = x[((b * NT + fr) * NJ + j) * NF + f];
            int i2 = f & ~1;
            float dv = expf(cdiv * (float)i2);
            float pe;
            if ((f & 1) == 0) pe = sinf((float)j * dv) + sinf((float)fr * dv);
            else              pe = cosf((float)j * dv) + cosf((float)fr * dv);
            s_xw[s][u] = xv + pe;
        }
        __syncthreads();
        // accumulate q/k/v for this chunk
        for (int uf = 0; uf < 32; ++uf) {
            int f = fc + uf;
            float wq  = Wq[f * NHD + col];
            float wk  = Wk[f * NHD + col];
            float wvl = Wv[f * NHD + col];
#pragma unroll
            for (int u = 0; u < 17; ++u) {
                int s = wv + 4 * u;
                if (s < NS) {
                    float a = s_xw[s][uf];      // broadcast read
                    acc0[u] = fmaf(a, wq,  acc0[u]);
                    acc1[u] = fmaf(a, wk,  acc1[u]);
                    acc2[u] = fmaf(a, wvl, acc2[u]);
                }
            }
        }
    }

    // write projections to LDS (q pre-scaled by 1/sqrt(DH)=1/8)
#pragma unroll
    for (int u = 0; u < 17; ++u) {
        int s = wv + 4 * u;
        if (s < NS) {
            s_q[s][lane]  = acc0[u] * 0.125f;
            s_kT[lane][s] = acc1[u];
            s_v[s][lane]  = fmaxf(acc2[u], 0.0f);
        }
    }
    __syncthreads();

    // ---- attention: wave wv owns rows r = wv, wv+4, ... ----
    for (int r = wv; r < NS; r += 4) {
        const int ir = r / NJ;          // frame index of query row (0/1/2)
        float sc0 = 0.f, sc1 = 0.f;
        const int c1 = 64 + (lane & 1); // cols 64,65 handled by lanes 0,1
#pragma unroll
        for (int d = 0; d < NDH; ++d) {
            float qd = s_q[r][d];                    // broadcast
            sc0 = fmaf(qd, s_kT[d][lane], sc0);      // col = lane
            sc1 = fmaf(qd, s_kT[d][c1],   sc1);      // col = 64/65
        }
        // domain mask: zero blocks (frame0,frame2) and (frame2,frame0)
        int ic = lane / NJ;
        if ((ir == 0 && ic == 2) || (ir == 2 && ic == 0)) sc0 = 0.f;
        if (ir == 0) sc1 = 0.f;                      // cols 64,65 are frame 2
        float hi1 = (lane < 2) ? sc1 : -INFINITY;

        // row max over masked scores
        float mx = fmaxf(sc0, hi1);
#pragma unroll
        for (int off = 32; off; off >>= 1) mx = fmaxf(mx, __shfl_xor(mx, off));
        float thr = mx * (1.0f / 9.0f);

        // abs-threshold -> NEG
        float e0 = (fabsf(sc0) <= thr) ? NEGV : sc0;
        float e1 = (lane < 2) ? ((fabsf(sc1) <= thr) ? NEGV : sc1) : -INFINITY;

        // softmax
        float M2 = fmaxf(e0, e1);
#pragma unroll
        for (int off = 32; off; off >>= 1) M2 = fmaxf(M2, __shfl_xor(M2, off));
        float p0 = __expf(e0 - M2);
        float p1 = (lane < 2) ? __expf(e1 - M2) : 0.f;
        float sm = p0 + p1;
#pragma unroll
        for (int off = 32; off; off >>= 1) sm += __shfl_xor(sm, off);
        float inv = 1.0f / sm;

        // PV: out[r][lane] = sum_j p_j * v[j][lane]
        float o = 0.f;
#pragma unroll
        for (int j = 0; j < 64; ++j) {
            float pj = __shfl(p0, j);
            o = fmaf(pj, s_v[j][lane], o);
        }
        o = fmaf(__shfl(p1, 0), s_v[64][lane], o);
        o = fmaf(__shfl(p1, 1), s_v[65][lane], o);
        s_q[r][lane] = o * inv;         // overwrite q row (already consumed)
    }
    __syncthreads();

    // ---- Wcls: out2[j][d] = sum_s att[s][d] * Wcls[s][j] + bcls[j] ----
    float* obase = out + ((b * (NW * NJ)) + w * NJ) * NHD + h * NDH;
    for (int idx = tid; idx < NJ * NDH; idx += 256) {
        int j = idx >> 6;
        int d = idx & 63;
        float a = bcls[j];
        for (int s = 0; s < NS; ++s)
            a = fmaf(s_q[s][d], Wcls[s * NJ + j], a);
        obase[j * NHD + d] = a;
    }
}

// ---------------------------------------------------------------------------
// Kernel B: y = relu(row @ Wft + bft); custom LayerNorm (ddof=1, eps on std)
// In-place on d_out. 16 rows per block, 256 threads.
// ---------------------------------------------------------------------------
__global__ __launch_bounds__(256) void ft_ln_kernel(
    const float* __restrict__ Wft, const float* __restrict__ bft,
    const float* __restrict__ a2, const float* __restrict__ b2,
    float* __restrict__ out)
{
    __shared__ float sA[16 * NOUT];     // 32 KB
    const int tid = threadIdx.x;
    const int base = blockIdx.x * (16 * NOUT);

    for (int idx = tid; idx < 16 * NOUT; idx += 256) sA[idx] = out[base + idx];
    __syncthreads();

    float a0[16], a1[16];
    const float bf0 = bft[tid], bf1 = bft[tid + 256];
#pragma unroll
    for (int r = 0; r < 16; ++r) { a0[r] = bf0; a1[r] = bf1; }

    for (int f = 0; f < NOUT; ++f) {
        float w0 = Wft[f * NOUT + tid];
        float w1 = Wft[f * NOUT + tid + 256];
#pragma unroll
        for (int r = 0; r < 16; ++r) {
            float a = sA[r * NOUT + f];          // broadcast
            a0[r] = fmaf(a, w0, a0[r]);
            a1[r] = fmaf(a, w1, a1[r]);
        }
    }
    __syncthreads();
#pragma unroll
    for (int r = 0; r < 16; ++r) {
        sA[r * NOUT + tid]       = fmaxf(a0[r], 0.f);
        sA[r * NOUT + tid + 256] = fmaxf(a1[r], 0.f);
    }
    __syncthreads();

    const int lane = tid & 63, wv = tid >> 6;
    for (int r = wv * 4; r < wv * 4 + 4; ++r) {
        float s = 0.f, sq = 0.f;
        float vals[8];
#pragma unroll
        for (int u = 0; u < 8; ++u) {
            float y = sA[r * NOUT + u * 64 + lane];
            vals[u] = y;
            s += y;
            sq = fmaf(y, y, sq);
        }
#pragma unroll
        for (int off = 32; off; off >>= 1) {
            s  += __shfl_xor(s,  off);
            sq += __shfl_xor(sq, off);
        }
        float mean = s * (1.0f / 512.0f);
        float var  = fmaxf((sq - 512.0f * mean * mean) * (1.0f / 511.0f), 0.0f);
        float inv  = 1.0f / (sqrtf(var) + 1e-6f);
#pragma unroll
        for (int u = 0; u < 8; ++u) {
            int c = u * 64 + lane;
            out[base + r * NOUT + c] = a2[c] * (vals[u] - mean) * inv + b2[c];
        }
    }
}

extern "C" void kernel_launch(void* const* d_in, const int* in_sizes, int n_in,
                              void* d_out, int out_size, void* d_ws, size_t ws_size,
                              hipStream_t stream) {
    (void)in_sizes; (void)n_in; (void)d_ws; (void)ws_size; (void)out_size;
    const float* x    = (const float*)d_in[0];
    const float* Wq   = (const float*)d_in[1];
    const float* bq   = (const float*)d_in[2];
    const float* Wk   = (const float*)d_in[3];
    const float* bk   = (const float*)d_in[4];
    const float* Wv   = (const float*)d_in[5];
    const float* bv   = (const float*)d_in[6];
    const float* Wcls = (const float*)d_in[7];
    const float* bcls = (const float*)d_in[8];
    const float* Wft  = (const float*)d_in[9];
    const float* bft  = (const float*)d_in[10];
    const float* a2   = (const float*)d_in[11];
    const float* b2   = (const float*)d_in[12];
    float* out = (float*)d_out;

    attn_kernel<<<NB * NW * NH, 256, 0, stream>>>(x, Wq, bq, Wk, bk, Wv, bv,
                                                  Wcls, bcls, out);
    ft_ln_kernel<<<(NB * NW * NJ) / 16, 256, 0, stream>>>(Wft, bft, a2, b2, out);
}

// Round 3
// 545.226 us; speedup vs baseline: 4.4120x; 4.4120x over previous
//
#include <hip/hip_runtime.h>
#include <math.h>

#define NB 128
#define NT 8
#define NJ 22
#define NF 128
#define NH 8
#define NDH 64
#define NS 66     // 3*NJ
#define NW 6      // NT-2
#define NOUT 512
#define NHD 512   // NH*NDH
#define NEGV -9e15f
#define HPB 4     // heads per block

typedef short bf16x8 __attribute__((ext_vector_type(8)));
typedef float f32x4  __attribute__((ext_vector_type(4)));

// ---- LDS regions (ushort offsets) ----
#define XWPH 0        // [66][128] x+PE hi, XOR-swizzled chunks
#define XWPL 8448     // [66][128] x+PE lo
#define QH   16896    // [66][72] q hi   (P [66][72] bf16 aliases this after scores)
#define QL   21648    // [66][72] q lo
#define PP   16896
#define KH   26400    // [66][72] k hi   (OT fp32 [64][76] aliases KH/KL after scores)
#define KL   31152    // [66][72] k lo
#define OTF_U 26400   // float* base (byte 52800), 64*76 floats -> ends at ushort 36128
#define VT   36128    // [64][72] relu(v) transposed bf16
#define LDS_USHORT 40736   // 81472 bytes

__device__ __forceinline__ unsigned short bfc(float f) {
    union { float f; unsigned u; } v; v.f = f;
    unsigned r = v.u + 0x7FFFu + ((v.u >> 16) & 1u);
    return (unsigned short)(r >> 16);
}
__device__ __forceinline__ float b2f(unsigned short h) {
    union { unsigned u; float f; } v; v.u = ((unsigned)h) << 16;
    return v.f;
}

__global__ __launch_bounds__(256) void attn_kernel(
    const float* __restrict__ x,
    const float* __restrict__ Wq, const float* __restrict__ bq,
    const float* __restrict__ Wk, const float* __restrict__ bk,
    const float* __restrict__ Wv, const float* __restrict__ bv,
    const float* __restrict__ Wcls, const float* __restrict__ bcls,
    float* __restrict__ out)
{
    __shared__ __align__(16) unsigned short lds[LDS_USHORT];
    float* OTf = (float*)&lds[OTF_U];   // [64][76] fp32, aliases K region

    const int tid  = threadIdx.x;
    const int lane = tid & 63;
    const int wv   = tid >> 6;          // wave 0..3
    const int l15  = lane & 15;
    const int lg   = lane >> 4;         // 0..3
    const int bid  = blockIdx.x;
    const int hb   = bid & 1;           // head half (heads hb*4 .. hb*4+3)
    const int w    = (bid >> 1) % NW;
    const int b    = bid / (2 * NW);

    // ---- stage x + PE as bf16 hi/lo, XOR-swizzled [66][128] ----
    const float cdiv = -0.0719557841560639f;   // -ln(10000)/128
    for (int idx = tid; idx < NS * NF; idx += 256) {
        int s = idx >> 7, f = idx & 127;
        int i = (s >= 44) ? 2 : ((s >= 22) ? 1 : 0);
        int j = s - i * NJ;
        int fr = w + i;
        float xv = x[((b * NT + fr) * NJ + j) * NF + f];
        float dv = __expf(cdiv * (float)(f & ~1));
        float pe = ((f & 1) == 0) ? (__sinf((float)j * dv) + __sinf((float)fr * dv))
                                  : (__cosf((float)j * dv) + __cosf((float)fr * dv));
        float val = xv + pe;
        unsigned short hs = bfc(val);
        int addr = s * 128 + ((((f >> 3) ^ (s & 15))) << 3) + (f & 7);
        lds[XWPH + addr] = hs;
        lds[XWPL + addr] = bfc(val - b2f(hs));
    }

    // ---- Wcls A-fragments in registers (K = s, ks 0..1 only; s<=63) ----
    bf16x8 wfrag[2][2];
#pragma unroll
    for (int mt = 0; mt < 2; ++mt)
#pragma unroll
        for (int ks = 0; ks < 2; ++ks) {
            int j = mt * 16 + l15;
            bf16x8 t;
#pragma unroll
            for (int i = 0; i < 8; ++i) {
                int s = ks * 32 + lg * 8 + i;
                float v = (j < NJ) ? Wcls[s * NJ + j] : 0.f;
                t[i] = (short)bfc(v);
            }
            wfrag[mt][ks] = t;
        }
    __syncthreads();

    for (int hh = 0; hh < HPB; ++hh) {
        const int h = hb * HPB + hh;
        const int colg = h * 64 + wv * 16 + l15;
        const int d    = wv * 16 + l15;

        // ---- load W panel fragments hi/lo from global ----
        bf16x8 qbh[4], qbl[4], kbh[4], kbl[4], vbh[4];
#pragma unroll
        for (int ks = 0; ks < 4; ++ks) {
            bf16x8 th, tl, kh_, kl_, vh_;
#pragma unroll
            for (int i = 0; i < 8; ++i) {
                int f = ks * 32 + lg * 8 + i;
                float wq = Wq[f * NHD + colg];
                unsigned short hq = bfc(wq);
                th[i] = (short)hq; tl[i] = (short)bfc(wq - b2f(hq));
                float wk = Wk[f * NHD + colg];
                unsigned short hk = bfc(wk);
                kh_[i] = (short)hk; kl_[i] = (short)bfc(wk - b2f(hk));
                vh_[i] = (short)bfc(Wv[f * NHD + colg]);
            }
            qbh[ks] = th; qbl[ks] = tl; kbh[ks] = kh_; kbl[ks] = kl_; vbh[ks] = vh_;
        }
        const float bqv = bq[colg], bkv = bk[colg], bvv = bv[colg];

        // ---- QKV projections: hi/lo triple-MFMA for q,k; single for v ----
        for (int mt = 0; mt < 5; ++mt) {
            f32x4 aq = {0,0,0,0}, ak = {0,0,0,0}, av = {0,0,0,0};
            int rowc = mt * 16 + l15; if (rowc > 65) rowc = 65;
#pragma unroll
            for (int ks = 0; ks < 4; ++ks) {
                int sw = rowc * 128 + (((ks * 4 + lg) ^ (rowc & 15)) << 3);
                bf16x8 ah = *(const bf16x8*)&lds[XWPH + sw];
                bf16x8 al = *(const bf16x8*)&lds[XWPL + sw];
                aq = __builtin_amdgcn_mfma_f32_16x16x32_bf16(ah, qbh[ks], aq, 0, 0, 0);
                aq = __builtin_amdgcn_mfma_f32_16x16x32_bf16(ah, qbl[ks], aq, 0, 0, 0);
                aq = __builtin_amdgcn_mfma_f32_16x16x32_bf16(al, qbh[ks], aq, 0, 0, 0);
                ak = __builtin_amdgcn_mfma_f32_16x16x32_bf16(ah, kbh[ks], ak, 0, 0, 0);
                ak = __builtin_amdgcn_mfma_f32_16x16x32_bf16(ah, kbl[ks], ak, 0, 0, 0);
                ak = __builtin_amdgcn_mfma_f32_16x16x32_bf16(al, kbh[ks], ak, 0, 0, 0);
                av = __builtin_amdgcn_mfma_f32_16x16x32_bf16(ah, vbh[ks], av, 0, 0, 0);
            }
#pragma unroll
            for (int r = 0; r < 4; ++r) {
                int s = mt * 16 + lg * 4 + r;
                if (s < NS) {
                    float qv = (aq[r] + bqv) * 0.125f;
                    unsigned short qh_ = bfc(qv);
                    lds[QH + s * 72 + d] = qh_;
                    lds[QL + s * 72 + d] = bfc(qv - b2f(qh_));
                    float kv = ak[r] + bkv;
                    unsigned short kh2 = bfc(kv);
                    lds[KH + s * 72 + d] = kh2;
                    lds[KL + s * 72 + d] = bfc(kv - b2f(kh2));
                    lds[VT + d * 72 + s] = bfc(fmaxf(av[r] + bvv, 0.f));
                }
            }
        }
        __syncthreads();   // b1: q,k,VT ready

        // ---- scores (triple-MFMA) + mask + threshold + softmax ----
        float pst[2][5][4];
#pragma unroll
        for (int t = 0; t < 2; ++t) {
            const int mt = (t == 0) ? wv : 4;
            const bool act = (t == 0) || (wv == 0);
            if (act) {
                int rowc = mt * 16 + l15; if (rowc > 65) rowc = 65;
                bf16x8 qh2[2], ql2[2];
#pragma unroll
                for (int ks = 0; ks < 2; ++ks) {
                    qh2[ks] = *(const bf16x8*)&lds[QH + rowc * 72 + ks * 32 + lg * 8];
                    ql2[ks] = *(const bf16x8*)&lds[QL + rowc * 72 + ks * 32 + lg * 8];
                }
                f32x4 c[5];
#pragma unroll
                for (int nt = 0; nt < 5; ++nt) {
                    f32x4 acc = {0,0,0,0};
                    int colr = nt * 16 + l15; if (colr > 65) colr = 65;
#pragma unroll
                    for (int ks = 0; ks < 2; ++ks) {
                        bf16x8 khf = *(const bf16x8*)&lds[KH + colr * 72 + ks * 32 + lg * 8];
                        bf16x8 klf = *(const bf16x8*)&lds[KL + colr * 72 + ks * 32 + lg * 8];
                        acc = __builtin_amdgcn_mfma_f32_16x16x32_bf16(qh2[ks], khf, acc, 0, 0, 0);
                        acc = __builtin_amdgcn_mfma_f32_16x16x32_bf16(qh2[ks], klf, acc, 0, 0, 0);
                        acc = __builtin_amdgcn_mfma_f32_16x16x32_bf16(ql2[ks], khf, acc, 0, 0, 0);
                    }
                    c[nt] = acc;
                }
#pragma unroll
                for (int r = 0; r < 4; ++r) {
                    int srow = mt * 16 + lg * 4 + r;
                    int fi = (srow >= 44) ? 2 : ((srow >= 22) ? 1 : 0);
                    float sv[5];
                    float mv = -INFINITY;
#pragma unroll
                    for (int nt = 0; nt < 5; ++nt) {
                        int j = nt * 16 + l15;
                        int fj = (j >= 44) ? 2 : ((j >= 22) ? 1 : 0);
                        float s = c[nt][r];
                        if ((fi == 0 && fj == 2) || (fi == 2 && fj == 0)) s = 0.f;
                        sv[nt] = s;
                        if (j < NS) mv = fmaxf(mv, s);
                    }
#pragma unroll
                    for (int off = 1; off < 16; off <<= 1) mv = fmaxf(mv, __shfl_xor(mv, off));
                    float thr = mv * (1.f / 9.f);
                    float ev[5];
                    float M2 = -INFINITY;
#pragma unroll
                    for (int nt = 0; nt < 5; ++nt) {
                        int j = nt * 16 + l15;
                        float e = (j < NS && fabsf(sv[nt]) > thr) ? sv[nt] : NEGV;
                        ev[nt] = e;
                        M2 = fmaxf(M2, e);
                    }
#pragma unroll
                    for (int off = 1; off < 16; off <<= 1) M2 = fmaxf(M2, __shfl_xor(M2, off));
                    float sum = 0.f;
#pragma unroll
                    for (int nt = 0; nt < 5; ++nt) {
                        float p = __expf(ev[nt] - M2);
                        pst[t][nt][r] = p;
                        sum += p;
                    }
#pragma unroll
                    for (int off = 1; off < 16; off <<= 1) sum += __shfl_xor(sum, off);
                    float inv = 1.f / sum;
#pragma unroll
                    for (int nt = 0; nt < 5; ++nt) pst[t][nt][r] *= inv;
                }
                // write P into the (same-band) Q alias — safe pre-barrier:
                // this wave is the only reader of its own Q band.
#pragma unroll
                for (int r = 0; r < 4; ++r) {
                    int srow = mt * 16 + lg * 4 + r;
                    if (srow < NS) {
#pragma unroll
                        for (int nt = 0; nt < 4; ++nt)
                            lds[PP + srow * 72 + nt * 16 + l15] = bfc(pst[t][nt][r]);
                        if (l15 < 2) lds[PP + srow * 72 + 64 + l15] = bfc(pst[t][4][r]);
                    }
                }
            }
        }
        __syncthreads();   // b3: P ready; all K reads done (OTf may overwrite K)

        // ---- PV: OT[d][s'] = sum_s P[s'][s] V[s][d]  (fp32 OT) ----
#pragma unroll
        for (int t5 = 0; t5 < 5; ++t5) {
            int tile = wv * 5 + t5;
            int mt = tile >> 2, nt = tile & 3;
            int rowc = mt * 16 + l15; if (rowc > 65) rowc = 65;
            int dn = nt * 16 + l15;
            f32x4 acc = {0,0,0,0};
#pragma unroll
            for (int ks = 0; ks < 2; ++ks) {
                bf16x8 pa = *(const bf16x8*)&lds[PP + rowc * 72 + ks * 32 + lg * 8];
                bf16x8 vb = *(const bf16x8*)&lds[VT + dn * 72 + ks * 32 + lg * 8];
                acc = __builtin_amdgcn_mfma_f32_16x16x32_bf16(pa, vb, acc, 0, 0, 0);
            }
            float v64 = b2f(lds[VT + dn * 72 + 64]);
            float v65 = b2f(lds[VT + dn * 72 + 65]);
#pragma unroll
            for (int r = 0; r < 4; ++r) {
                int s2 = mt * 16 + lg * 4 + r;
                if (s2 < NS) {
                    float p64 = b2f(lds[PP + s2 * 72 + 64]);
                    float p65 = b2f(lds[PP + s2 * 72 + 65]);
                    OTf[dn * 76 + s2] = acc[r] + p64 * v64 + p65 * v65;
                }
            }
        }
        __syncthreads();   // b4: OT ready

        // ---- Wcls: C[j][d] = sum_s Wcls[s][j] OT[d][s] (+ s=64,65 fp32 corr) ----
#pragma unroll
        for (int t = 0; t < 2; ++t) {
            f32x4 acc = {0,0,0,0};
#pragma unroll
            for (int ks = 0; ks < 2; ++ks) {
                f32x4 f0 = *(const f32x4*)&OTf[d * 76 + ks * 32 + lg * 8];
                f32x4 f1 = *(const f32x4*)&OTf[d * 76 + ks * 32 + lg * 8 + 4];
                bf16x8 bb;
#pragma unroll
                for (int i = 0; i < 4; ++i) {
                    bb[i]     = (short)bfc(f0[i]);
                    bb[i + 4] = (short)bfc(f1[i]);
                }
                acc = __builtin_amdgcn_mfma_f32_16x16x32_bf16(wfrag[t][ks], bb, acc, 0, 0, 0);
            }
            float o64 = OTf[d * 76 + 64];
            float o65 = OTf[d * 76 + 65];
#pragma unroll
            for (int r = 0; r < 4; ++r) {
                int jj = t * 16 + lg * 4 + r;
                if (jj < NJ) {
                    float res = acc[r] + Wcls[64 * NJ + jj] * o64
                                       + Wcls[65 * NJ + jj] * o65 + bcls[jj];
                    out[((b * (NW * NJ) + w * NJ + jj) * NHD) + h * 64 + wv * 16 + l15] = res;
                }
            }
        }
        __syncthreads();   // b5: OT/Q/VT regions free for next head
    }
}

// ---------------------------------------------------------------------------
// Kernel B: y = relu(row @ Wft + bft); custom LayerNorm (ddof=1, eps on std)
// In-place on d_out. 16 rows per block, 256 threads. (fp32)
// ---------------------------------------------------------------------------
__global__ __launch_bounds__(256) void ft_ln_kernel(
    const float* __restrict__ Wft, const float* __restrict__ bft,
    const float* __restrict__ a2, const float* __restrict__ b2,
    float* __restrict__ out)
{
    __shared__ float sA[16 * NOUT];
    const int tid = threadIdx.x;
    const int base = blockIdx.x * (16 * NOUT);

    for (int idx = tid; idx < 16 * NOUT; idx += 256) sA[idx] = out[base + idx];
    __syncthreads();

    float a0[16], a1[16];
    const float bf0 = bft[tid], bf1 = bft[tid + 256];
#pragma unroll
    for (int r = 0; r < 16; ++r) { a0[r] = bf0; a1[r] = bf1; }

    for (int f = 0; f < NOUT; ++f) {
        float w0 = Wft[f * NOUT + tid];
        float w1 = Wft[f * NOUT + tid + 256];
#pragma unroll
        for (int r = 0; r < 16; ++r) {
            float a = sA[r * NOUT + f];
            a0[r] = fmaf(a, w0, a0[r]);
            a1[r] = fmaf(a, w1, a1[r]);
        }
    }
    __syncthreads();
#pragma unroll
    for (int r = 0; r < 16; ++r) {
        sA[r * NOUT + tid]       = fmaxf(a0[r], 0.f);
        sA[r * NOUT + tid + 256] = fmaxf(a1[r], 0.f);
    }
    __syncthreads();

    const int lane = tid & 63, wvv = tid >> 6;
    for (int r = wvv * 4; r < wvv * 4 + 4; ++r) {
        float s = 0.f, sq = 0.f;
        float vals[8];
#pragma unroll
        for (int u = 0; u < 8; ++u) {
            float y = sA[r * NOUT + u * 64 + lane];
            vals[u] = y;
            s += y;
            sq = fmaf(y, y, sq);
        }
#pragma unroll
        for (int off = 32; off; off >>= 1) {
            s  += __shfl_xor(s,  off);
            sq += __shfl_xor(sq, off);
        }
        float mean = s * (1.0f / 512.0f);
        float var  = fmaxf((sq - 512.0f * mean * mean) * (1.0f / 511.0f), 0.0f);
        float inv  = 1.0f / (sqrtf(var) + 1e-6f);
#pragma unroll
        for (int u = 0; u < 8; ++u) {
            int c = u * 64 + lane;
            out[base + r * NOUT + c] = a2[c] * (vals[u] - mean) * inv + b2[c];
        }
    }
}

extern "C" void kernel_launch(void* const* d_in, const int* in_sizes, int n_in,
                              void* d_out, int out_size, void* d_ws, size_t ws_size,
                              hipStream_t stream) {
    (void)in_sizes; (void)n_in; (void)d_ws; (void)ws_size; (void)out_size;
    const float* x    = (const float*)d_in[0];
    const float* Wq   = (const float*)d_in[1];
    const float* bq   = (const float*)d_in[2];
    const float* Wk   = (const float*)d_in[3];
    const float* bk   = (const float*)d_in[4];
    const float* Wv   = (const float*)d_in[5];
    const float* bv   = (const float*)d_in[6];
    const float* Wcls = (const float*)d_in[7];
    const float* bcls = (const float*)d_in[8];
    const float* Wft  = (const float*)d_in[9];
    const float* bft  = (const float*)d_in[10];
    const float* a2   = (const float*)d_in[11];
    const float* b2   = (const float*)d_in[12];
    float* out = (float*)d_out;

    attn_kernel<<<NB * NW * 2, 256, 0, stream>>>(x, Wq, bq, Wk, bk, Wv, bv,
                                                 Wcls, bcls, out);
    ft_ln_kernel<<<(NB * NW * NJ) / 16, 256, 0, stream>>>(Wft, bft, a2, b2, out);
}

// Round 4
// 544.540 us; speedup vs baseline: 4.4175x; 1.0013x over previous
//
#include <hip/hip_runtime.h>
#include <math.h>

#define NB 128
#define NT 8
#define NJ 22
#define NF 128
#define NH 8
#define NDH 64
#define NS 66     // 3*NJ
#define NW 6      // NT-2
#define NOUT 512
#define NHD 512   // NH*NDH
#define NEGV -9e15f
#define HPB 4     // heads per block

typedef short bf16x8 __attribute__((ext_vector_type(8)));
typedef float f32x4  __attribute__((ext_vector_type(4)));

// ---- LDS regions (ushort offsets) ----
#define XWPH 0        // [66][128] x+PE hi, XOR-swizzled chunks
#define XWPL 8448     // [66][128] x+PE lo
#define QH   16896    // [66][72] q hi   (P_hi aliases after scores)
#define QL   21648    // [66][72] q lo   (P_lo aliases after scores)
#define KH   26400    // [66][72] k hi   (OT fp32 [64][76] aliases KH/KL)
#define KL   31152    // [66][72] k lo
#define OTF_U 26400   // float* base (byte 52800), 64*76 floats
#define VT   36128    // [64][72] relu(v) transposed bf16
#define LDS_USHORT 40736   // 81472 bytes

// ---- workspace layout (ushort offsets) ----
#define WQH 0
#define WQL 65536
#define WKH 131072
#define WKL 196608
#define WVT 262144
#define WFH 327680     // WftT hi [512][512]
#define WFL 589824     // WftT lo
#define WS_NEED_BYTES 1703936

__device__ __forceinline__ unsigned short bfc(float f) {
    union { float f; unsigned u; } v; v.f = f;
    unsigned r = v.u + 0x7FFFu + ((v.u >> 16) & 1u);
    return (unsigned short)(r >> 16);
}
__device__ __forceinline__ float b2f(unsigned short h) {
    union { unsigned u; float f; } v; v.u = ((unsigned)h) << 16;
    return v.f;
}

// ---------------------------------------------------------------------------
// prep: transpose + bf16 hi/lo split of Wq/Wk/Wv/Wft into ws
// ---------------------------------------------------------------------------
__global__ __launch_bounds__(256) void prep_kernel(
    const float* __restrict__ Wq, const float* __restrict__ Wk,
    const float* __restrict__ Wv, const float* __restrict__ Wft,
    unsigned short* __restrict__ ws)
{
    int idx = blockIdx.x * 256 + threadIdx.x;
    if (idx < 196608) {
        int m = idx >> 16;            // 0=q,1=k,2=v
        int r = idx & 65535;          // r = col*128 + f
        int col = r >> 7, f = r & 127;
        const float* W = (m == 0) ? Wq : ((m == 1) ? Wk : Wv);
        float v = W[f * NHD + col];
        unsigned short h = bfc(v);
        if (m == 0)      { ws[WQH + r] = h; ws[WQL + r] = bfc(v - b2f(h)); }
        else if (m == 1) { ws[WKH + r] = h; ws[WKL + r] = bfc(v - b2f(h)); }
        else             { ws[WVT + r] = h; }
    } else {
        int r = idx - 196608;         // r = col*512 + f
        int col = r >> 9, f = r & 511;
        float v = Wft[f * NOUT + col];
        unsigned short h = bfc(v);
        ws[WFH + r] = h;
        ws[WFL + r] = bfc(v - b2f(h));
    }
}

// ---------------------------------------------------------------------------
// attn v2: fused (x+PE) -> QKV (ks-outer, ws fragments) -> attention -> Wcls
// ---------------------------------------------------------------------------
__global__ __launch_bounds__(256) void attn_kernel2(
    const float* __restrict__ x,
    const float* __restrict__ bq, const float* __restrict__ bk,
    const float* __restrict__ bv,
    const float* __restrict__ Wcls, const float* __restrict__ bcls,
    const unsigned short* __restrict__ ws,
    float* __restrict__ out)
{
    __shared__ __align__(16) unsigned short lds[LDS_USHORT];
    float* OTf = (float*)&lds[OTF_U];

    const int tid  = threadIdx.x;
    const int lane = tid & 63;
    const int wv   = tid >> 6;
    const int l15  = lane & 15;
    const int lg   = lane >> 4;
    const int bid  = blockIdx.x;
    const int hb   = bid & 1;
    const int w    = (bid >> 1) % NW;
    const int b    = bid / (2 * NW);

    // ---- stage x + PE as bf16 hi/lo, XOR-swizzled [66][128] ----
    const float cdiv = -0.0719557841560639f;
    for (int idx = tid; idx < NS * NF; idx += 256) {
        int s = idx >> 7, f = idx & 127;
        int i = (s >= 44) ? 2 : ((s >= 22) ? 1 : 0);
        int j = s - i * NJ;
        int fr = w + i;
        float xv = x[((b * NT + fr) * NJ + j) * NF + f];
        float dv = __expf(cdiv * (float)(f & ~1));
        float pe = ((f & 1) == 0) ? (__sinf((float)j * dv) + __sinf((float)fr * dv))
                                  : (__cosf((float)j * dv) + __cosf((float)fr * dv));
        float val = xv + pe;
        unsigned short hs = bfc(val);
        int addr = s * 128 + ((((f >> 3) ^ (s & 15))) << 3) + (f & 7);
        lds[XWPH + addr] = hs;
        lds[XWPL + addr] = bfc(val - b2f(hs));
    }

    // ---- Wcls A-fragments in registers ----
    bf16x8 wfrag[2][2];
#pragma unroll
    for (int mt = 0; mt < 2; ++mt)
#pragma unroll
        for (int ks = 0; ks < 2; ++ks) {
            int j = mt * 16 + l15;
            bf16x8 t;
#pragma unroll
            for (int i = 0; i < 8; ++i) {
                int s = ks * 32 + lg * 8 + i;
                float v = (j < NJ) ? Wcls[s * NJ + j] : 0.f;
                t[i] = (short)bfc(v);
            }
            wfrag[mt][ks] = t;
        }
    __syncthreads();

    for (int hh = 0; hh < HPB; ++hh) {
        const int h = hb * HPB + hh;
        const int colg = h * 64 + wv * 16 + l15;
        const int d    = wv * 16 + l15;

        // ---- W fragments: 20 vector loads from ws ----
        bf16x8 qbh[4], qbl[4], kbh[4], kbl[4], vbh[4];
#pragma unroll
        for (int ks = 0; ks < 4; ++ks) {
            int o = colg * 128 + ks * 32 + lg * 8;
            qbh[ks] = *(const bf16x8*)&ws[WQH + o];
            qbl[ks] = *(const bf16x8*)&ws[WQL + o];
            kbh[ks] = *(const bf16x8*)&ws[WKH + o];
            kbl[ks] = *(const bf16x8*)&ws[WKL + o];
            vbh[ks] = *(const bf16x8*)&ws[WVT + o];
        }
        const float bqv = bq[colg], bkv = bk[colg], bvv = bv[colg];

        // ---- QKV: ks-outer, 15 accumulators ----
        f32x4 aq[5], ak[5], av[5];
#pragma unroll
        for (int mt = 0; mt < 5; ++mt) {
            aq[mt] = (f32x4){0,0,0,0}; ak[mt] = (f32x4){0,0,0,0}; av[mt] = (f32x4){0,0,0,0};
        }
#pragma unroll
        for (int ks = 0; ks < 4; ++ks) {
#pragma unroll
            for (int mt = 0; mt < 5; ++mt) {
                int rowc = mt * 16 + l15; if (rowc > 65) rowc = 65;
                int sw = rowc * 128 + (((ks * 4 + lg) ^ (rowc & 15)) << 3);
                bf16x8 ah = *(const bf16x8*)&lds[XWPH + sw];
                bf16x8 al = *(const bf16x8*)&lds[XWPL + sw];
                aq[mt] = __builtin_amdgcn_mfma_f32_16x16x32_bf16(ah, qbh[ks], aq[mt], 0, 0, 0);
                aq[mt] = __builtin_amdgcn_mfma_f32_16x16x32_bf16(ah, qbl[ks], aq[mt], 0, 0, 0);
                aq[mt] = __builtin_amdgcn_mfma_f32_16x16x32_bf16(al, qbh[ks], aq[mt], 0, 0, 0);
                ak[mt] = __builtin_amdgcn_mfma_f32_16x16x32_bf16(ah, kbh[ks], ak[mt], 0, 0, 0);
                ak[mt] = __builtin_amdgcn_mfma_f32_16x16x32_bf16(ah, kbl[ks], ak[mt], 0, 0, 0);
                ak[mt] = __builtin_amdgcn_mfma_f32_16x16x32_bf16(al, kbh[ks], ak[mt], 0, 0, 0);
                av[mt] = __builtin_amdgcn_mfma_f32_16x16x32_bf16(ah, vbh[ks], av[mt], 0, 0, 0);
            }
        }
#pragma unroll
        for (int mt = 0; mt < 5; ++mt) {
#pragma unroll
            for (int r = 0; r < 4; ++r) {
                int s = mt * 16 + lg * 4 + r;
                if (s < NS) {
                    float qv = (aq[mt][r] + bqv) * 0.125f;
                    unsigned short qh_ = bfc(qv);
                    lds[QH + s * 72 + d] = qh_;
                    lds[QL + s * 72 + d] = bfc(qv - b2f(qh_));
                    float kv = ak[mt][r] + bkv;
                    unsigned short kh2 = bfc(kv);
                    lds[KH + s * 72 + d] = kh2;
                    lds[KL + s * 72 + d] = bfc(kv - b2f(kh2));
                    lds[VT + d * 72 + s] = bfc(fmaxf(av[mt][r] + bvv, 0.f));
                }
            }
        }
        __syncthreads();   // b1: q,k,VT ready

        // ---- scores + mask + threshold + softmax -> P (hi/lo) ----
#pragma unroll
        for (int t = 0; t < 2; ++t) {
            const int mt = (t == 0) ? wv : 4;
            const bool act = (t == 0) || (wv == 0);
            if (act) {
                int rowc = mt * 16 + l15; if (rowc > 65) rowc = 65;
                bf16x8 qh2[2], ql2[2];
#pragma unroll
                for (int ks = 0; ks < 2; ++ks) {
                    qh2[ks] = *(const bf16x8*)&lds[QH + rowc * 72 + ks * 32 + lg * 8];
                    ql2[ks] = *(const bf16x8*)&lds[QL + rowc * 72 + ks * 32 + lg * 8];
                }
                f32x4 c[5];
#pragma unroll
                for (int nt = 0; nt < 5; ++nt) {
                    f32x4 acc = {0,0,0,0};
                    int colr = nt * 16 + l15; if (colr > 65) colr = 65;
#pragma unroll
                    for (int ks = 0; ks < 2; ++ks) {
                        bf16x8 khf = *(const bf16x8*)&lds[KH + colr * 72 + ks * 32 + lg * 8];
                        bf16x8 klf = *(const bf16x8*)&lds[KL + colr * 72 + ks * 32 + lg * 8];
                        acc = __builtin_amdgcn_mfma_f32_16x16x32_bf16(qh2[ks], khf, acc, 0, 0, 0);
                        acc = __builtin_amdgcn_mfma_f32_16x16x32_bf16(qh2[ks], klf, acc, 0, 0, 0);
                        acc = __builtin_amdgcn_mfma_f32_16x16x32_bf16(ql2[ks], khf, acc, 0, 0, 0);
                    }
                    c[nt] = acc;
                }
#pragma unroll
                for (int r = 0; r < 4; ++r) {
                    int srow = mt * 16 + lg * 4 + r;
                    int fi = (srow >= 44) ? 2 : ((srow >= 22) ? 1 : 0);
                    float sv[5];
                    float mv = -INFINITY;
#pragma unroll
                    for (int nt = 0; nt < 5; ++nt) {
                        int j = nt * 16 + l15;
                        int fj = (j >= 44) ? 2 : ((j >= 22) ? 1 : 0);
                        float s = c[nt][r];
                        if ((fi == 0 && fj == 2) || (fi == 2 && fj == 0)) s = 0.f;
                        sv[nt] = s;
                        if (j < NS) mv = fmaxf(mv, s);
                    }
#pragma unroll
                    for (int off = 1; off < 16; off <<= 1) mv = fmaxf(mv, __shfl_xor(mv, off));
                    float thr = mv * (1.f / 9.f);
                    float ev[5];
                    float M2 = -INFINITY;
#pragma unroll
                    for (int nt = 0; nt < 5; ++nt) {
                        int j = nt * 16 + l15;
                        float e = (j < NS && fabsf(sv[nt]) > thr) ? sv[nt] : NEGV;
                        ev[nt] = e;
                        M2 = fmaxf(M2, e);
                    }
#pragma unroll
                    for (int off = 1; off < 16; off <<= 1) M2 = fmaxf(M2, __shfl_xor(M2, off));
                    float pv5[5];
                    float sum = 0.f;
#pragma unroll
                    for (int nt = 0; nt < 5; ++nt) {
                        float p = __expf(ev[nt] - M2);
                        pv5[nt] = p;
                        sum += p;
                    }
#pragma unroll
                    for (int off = 1; off < 16; off <<= 1) sum += __shfl_xor(sum, off);
                    float inv = 1.f / sum;
                    if (srow < NS) {
#pragma unroll
                        for (int nt = 0; nt < 5; ++nt) {
                            float p = pv5[nt] * inv;
                            unsigned short ph = bfc(p);
                            unsigned short pl = bfc(p - b2f(ph));
                            if (nt < 4) {
                                lds[QH + srow * 72 + nt * 16 + l15] = ph;
                                lds[QL + srow * 72 + nt * 16 + l15] = pl;
                            } else if (l15 < 2) {
                                lds[QH + srow * 72 + 64 + l15] = ph;
                                lds[QL + srow * 72 + 64 + l15] = pl;
                            }
                        }
                    }
                }
            }
        }
        __syncthreads();   // b3: P ready; K region free for OT

        // ---- PV: OT[d][s'] = P @ V  (P hi/lo, fp32 OT) ----
#pragma unroll
        for (int t5 = 0; t5 < 5; ++t5) {
            int tile = wv * 5 + t5;
            int mt = tile >> 2, nt = tile & 3;
            int rowc = mt * 16 + l15; if (rowc > 65) rowc = 65;
            int dn = nt * 16 + l15;
            f32x4 acc = {0,0,0,0};
#pragma unroll
            for (int ks = 0; ks < 2; ++ks) {
                bf16x8 pah = *(const bf16x8*)&lds[QH + rowc * 72 + ks * 32 + lg * 8];
                bf16x8 pal = *(const bf16x8*)&lds[QL + rowc * 72 + ks * 32 + lg * 8];
                bf16x8 vb  = *(const bf16x8*)&lds[VT + dn * 72 + ks * 32 + lg * 8];
                acc = __builtin_amdgcn_mfma_f32_16x16x32_bf16(pah, vb, acc, 0, 0, 0);
                acc = __builtin_amdgcn_mfma_f32_16x16x32_bf16(pal, vb, acc, 0, 0, 0);
            }
            float v64 = b2f(lds[VT + dn * 72 + 64]);
            float v65 = b2f(lds[VT + dn * 72 + 65]);
#pragma unroll
            for (int r = 0; r < 4; ++r) {
                int s2 = mt * 16 + lg * 4 + r;
                if (s2 < NS) {
                    float p64 = b2f(lds[QH + s2 * 72 + 64]) + b2f(lds[QL + s2 * 72 + 64]);
                    float p65 = b2f(lds[QH + s2 * 72 + 65]) + b2f(lds[QL + s2 * 72 + 65]);
                    OTf[dn * 76 + s2] = acc[r] + p64 * v64 + p65 * v65;
                }
            }
        }
        __syncthreads();   // b4: OT ready

        // ---- Wcls (OT hi/lo double-MFMA) ----
#pragma unroll
        for (int t = 0; t < 2; ++t) {
            f32x4 acc = {0,0,0,0};
#pragma unroll
            for (int ks = 0; ks < 2; ++ks) {
                f32x4 f0 = *(const f32x4*)&OTf[d * 76 + ks * 32 + lg * 8];
                f32x4 f1 = *(const f32x4*)&OTf[d * 76 + ks * 32 + lg * 8 + 4];
                bf16x8 bh_, bl_;
#pragma unroll
                for (int i = 0; i < 4; ++i) {
                    unsigned short h0 = bfc(f0[i]);
                    bh_[i] = (short)h0; bl_[i] = (short)bfc(f0[i] - b2f(h0));
                    unsigned short h1 = bfc(f1[i]);
                    bh_[i + 4] = (short)h1; bl_[i + 4] = (short)bfc(f1[i] - b2f(h1));
                }
                acc = __builtin_amdgcn_mfma_f32_16x16x32_bf16(wfrag[t][ks], bh_, acc, 0, 0, 0);
                acc = __builtin_amdgcn_mfma_f32_16x16x32_bf16(wfrag[t][ks], bl_, acc, 0, 0, 0);
            }
            float o64 = OTf[d * 76 + 64];
            float o65 = OTf[d * 76 + 65];
#pragma unroll
            for (int r = 0; r < 4; ++r) {
                int jj = t * 16 + lg * 4 + r;
                if (jj < NJ) {
                    float res = acc[r] + Wcls[64 * NJ + jj] * o64
                                       + Wcls[65 * NJ + jj] * o65 + bcls[jj];
                    out[((b * (NW * NJ) + w * NJ + jj) * NHD) + h * 64 + wv * 16 + l15] = res;
                }
            }
        }
        __syncthreads();   // b5: regions free for next head
    }
}

// ---------------------------------------------------------------------------
// ft v2: MFMA hi/lo GEMM [16,512]@[512,512] + bias + ReLU + custom LN
// ---------------------------------------------------------------------------
__global__ __launch_bounds__(256) void ft_ln2(
    const unsigned short* __restrict__ ws,
    const float* __restrict__ bft,
    const float* __restrict__ a2, const float* __restrict__ b2,
    float* __restrict__ out)
{
    __shared__ __align__(16) unsigned short sA[2 * 16 * 528];  // AH, AL
    __shared__ float red[2][4][16];
    const int tid = threadIdx.x, lane = tid & 63, wv = tid >> 6;
    const int l15 = lane & 15, lg = lane >> 4;
    const int base = blockIdx.x * (16 * NOUT);

    for (int idx = tid; idx < 16 * NOUT; idx += 256) {
        int r = idx >> 9, c = idx & 511;
        float v = out[base + idx];
        unsigned short h = bfc(v);
        sA[r * 528 + c] = h;
        sA[8448 + r * 528 + c] = bfc(v - b2f(h));
    }
    __syncthreads();

    f32x4 acc[8];
#pragma unroll
    for (int nt = 0; nt < 8; ++nt) acc[nt] = (f32x4){0,0,0,0};

#pragma unroll 4
    for (int ka = 0; ka < 16; ++ka) {
        bf16x8 ah = *(const bf16x8*)&sA[l15 * 528 + ka * 32 + lg * 8];
        bf16x8 al = *(const bf16x8*)&sA[8448 + l15 * 528 + ka * 32 + lg * 8];
#pragma unroll
        for (int nt = 0; nt < 8; ++nt) {
            int col = (wv * 8 + nt) * 16 + l15;
            bf16x8 bh = *(const bf16x8*)&ws[WFH + col * 512 + ka * 32 + lg * 8];
            bf16x8 bl = *(const bf16x8*)&ws[WFL + col * 512 + ka * 32 + lg * 8];
            acc[nt] = __builtin_amdgcn_mfma_f32_16x16x32_bf16(ah, bh, acc[nt], 0, 0, 0);
            acc[nt] = __builtin_amdgcn_mfma_f32_16x16x32_bf16(ah, bl, acc[nt], 0, 0, 0);
            acc[nt] = __builtin_amdgcn_mfma_f32_16x16x32_bf16(al, bh, acc[nt], 0, 0, 0);
        }
    }

    // bias + relu
#pragma unroll
    for (int nt = 0; nt < 8; ++nt) {
        int col = (wv * 8 + nt) * 16 + l15;
        float bfv = bft[col];
#pragma unroll
        for (int r = 0; r < 4; ++r) acc[nt][r] = fmaxf(acc[nt][r] + bfv, 0.f);
    }

    // per-row stats: partial over this wave's 128 cols, reduce over l15
    float ps[4], pq[4];
#pragma unroll
    for (int r = 0; r < 4; ++r) {
        float s = 0.f, q = 0.f;
#pragma unroll
        for (int nt = 0; nt < 8; ++nt) { s += acc[nt][r]; q = fmaf(acc[nt][r], acc[nt][r], q); }
        ps[r] = s; pq[r] = q;
    }
#pragma unroll
    for (int off = 1; off < 16; off <<= 1) {
#pragma unroll
        for (int r = 0; r < 4; ++r) {
            ps[r] += __shfl_xor(ps[r], off);
            pq[r] += __shfl_xor(pq[r], off);
        }
    }
    if (l15 == 0) {
#pragma unroll
        for (int r = 0; r < 4; ++r) {
            red[0][wv][lg * 4 + r] = ps[r];
            red[1][wv][lg * 4 + r] = pq[r];
        }
    }
    __syncthreads();

    float mean[4], inv[4];
#pragma unroll
    for (int r = 0; r < 4; ++r) {
        int row = lg * 4 + r;
        float s = red[0][0][row] + red[0][1][row] + red[0][2][row] + red[0][3][row];
        float q = red[1][0][row] + red[1][1][row] + red[1][2][row] + red[1][3][row];
        float m = s * (1.0f / 512.0f);
        float var = fmaxf((q - 512.0f * m * m) * (1.0f / 511.0f), 0.0f);
        mean[r] = m;
        inv[r] = 1.0f / (sqrtf(var) + 1e-6f);
    }
#pragma unroll
    for (int nt = 0; nt < 8; ++nt) {
        int col = (wv * 8 + nt) * 16 + l15;
        float av2 = a2[col], bv2 = b2[col];
#pragma unroll
        for (int r = 0; r < 4; ++r) {
            int row = lg * 4 + r;
            out[base + row * NOUT + col] = av2 * (acc[nt][r] - mean[r]) * inv[r] + bv2;
        }
    }
}

// ===========================================================================
// Fallback path (R3, proven): used only if ws_size < WS_NEED_BYTES
// ===========================================================================
__global__ __launch_bounds__(256) void attn_kernel(
    const float* __restrict__ x,
    const float* __restrict__ Wq, const float* __restrict__ bq,
    const float* __restrict__ Wk, const float* __restrict__ bk,
    const float* __restrict__ Wv, const float* __restrict__ bv,
    const float* __restrict__ Wcls, const float* __restrict__ bcls,
    float* __restrict__ out)
{
    __shared__ __align__(16) unsigned short lds[LDS_USHORT];
    float* OTf = (float*)&lds[OTF_U];

    const int tid  = threadIdx.x;
    const int lane = tid & 63;
    const int wv   = tid >> 6;
    const int l15  = lane & 15;
    const int lg   = lane >> 4;
    const int bid  = blockIdx.x;
    const int hb   = bid & 1;
    const int w    = (bid >> 1) % NW;
    const int b    = bid / (2 * NW);

    const float cdiv = -0.0719557841560639f;
    for (int idx = tid; idx < NS * NF; idx += 256) {
        int s = idx >> 7, f = idx & 127;
        int i = (s >= 44) ? 2 : ((s >= 22) ? 1 : 0);
        int j = s - i * NJ;
        int fr = w + i;
        float xv = x[((b * NT + fr) * NJ + j) * NF + f];
        float dv = __expf(cdiv * (float)(f & ~1));
        float pe = ((f & 1) == 0) ? (__sinf((float)j * dv) + __sinf((float)fr * dv))
                                  : (__cosf((float)j * dv) + __cosf((float)fr * dv));
        float val = xv + pe;
        unsigned short hs = bfc(val);
        int addr = s * 128 + ((((f >> 3) ^ (s & 15))) << 3) + (f & 7);
        lds[XWPH + addr] = hs;
        lds[XWPL + addr] = bfc(val - b2f(hs));
    }

    bf16x8 wfrag[2][2];
#pragma unroll
    for (int mt = 0; mt < 2; ++mt)
#pragma unroll
        for (int ks = 0; ks < 2; ++ks) {
            int j = mt * 16 + l15;
            bf16x8 t;
#pragma unroll
            for (int i = 0; i < 8; ++i) {
                int s = ks * 32 + lg * 8 + i;
                float v = (j < NJ) ? Wcls[s * NJ + j] : 0.f;
                t[i] = (short)bfc(v);
            }
            wfrag[mt][ks] = t;
        }
    __syncthreads();

    for (int hh = 0; hh < HPB; ++hh) {
        const int h = hb * HPB + hh;
        const int colg = h * 64 + wv * 16 + l15;
        const int d    = wv * 16 + l15;

        bf16x8 qbh[4], qbl[4], kbh[4], kbl[4], vbh[4];
#pragma unroll
        for (int ks = 0; ks < 4; ++ks) {
            bf16x8 th, tl, kh_, kl_, vh_;
#pragma unroll
            for (int i = 0; i < 8; ++i) {
                int f = ks * 32 + lg * 8 + i;
                float wq = Wq[f * NHD + colg];
                unsigned short hq = bfc(wq);
                th[i] = (short)hq; tl[i] = (short)bfc(wq - b2f(hq));
                float wk = Wk[f * NHD + colg];
                unsigned short hk = bfc(wk);
                kh_[i] = (short)hk; kl_[i] = (short)bfc(wk - b2f(hk));
                vh_[i] = (short)bfc(Wv[f * NHD + colg]);
            }
            qbh[ks] = th; qbl[ks] = tl; kbh[ks] = kh_; kbl[ks] = kl_; vbh[ks] = vh_;
        }
        const float bqv = bq[colg], bkv = bk[colg], bvv = bv[colg];

        for (int mt = 0; mt < 5; ++mt) {
            f32x4 aq = {0,0,0,0}, ak = {0,0,0,0}, av = {0,0,0,0};
            int rowc = mt * 16 + l15; if (rowc > 65) rowc = 65;
#pragma unroll
            for (int ks = 0; ks < 4; ++ks) {
                int sw = rowc * 128 + (((ks * 4 + lg) ^ (rowc & 15)) << 3);
                bf16x8 ah = *(const bf16x8*)&lds[XWPH + sw];
                bf16x8 al = *(const bf16x8*)&lds[XWPL + sw];
                aq = __builtin_amdgcn_mfma_f32_16x16x32_bf16(ah, qbh[ks], aq, 0, 0, 0);
                aq = __builtin_amdgcn_mfma_f32_16x16x32_bf16(ah, qbl[ks], aq, 0, 0, 0);
                aq = __builtin_amdgcn_mfma_f32_16x16x32_bf16(al, qbh[ks], aq, 0, 0, 0);
                ak = __builtin_amdgcn_mfma_f32_16x16x32_bf16(ah, kbh[ks], ak, 0, 0, 0);
                ak = __builtin_amdgcn_mfma_f32_16x16x32_bf16(ah, kbl[ks], ak, 0, 0, 0);
                ak = __builtin_amdgcn_mfma_f32_16x16x32_bf16(al, kbh[ks], ak, 0, 0, 0);
                av = __builtin_amdgcn_mfma_f32_16x16x32_bf16(ah, vbh[ks], av, 0, 0, 0);
            }
#pragma unroll
            for (int r = 0; r < 4; ++r) {
                int s = mt * 16 + lg * 4 + r;
                if (s < NS) {
                    float qv = (aq[r] + bqv) * 0.125f;
                    unsigned short qh_ = bfc(qv);
                    lds[QH + s * 72 + d] = qh_;
                    lds[QL + s * 72 + d] = bfc(qv - b2f(qh_));
                    float kv = ak[r] + bkv;
                    unsigned short kh2 = bfc(kv);
                    lds[KH + s * 72 + d] = kh2;
                    lds[KL + s * 72 + d] = bfc(kv - b2f(kh2));
                    lds[VT + d * 72 + s] = bfc(fmaxf(av[r] + bvv, 0.f));
                }
            }
        }
        __syncthreads();

        float pst[2][5][4];
#pragma unroll
        for (int t = 0; t < 2; ++t) {
            const int mt = (t == 0) ? wv : 4;
            const bool act = (t == 0) || (wv == 0);
            if (act) {
                int rowc = mt * 16 + l15; if (rowc > 65) rowc = 65;
                bf16x8 qh2[2], ql2[2];
#pragma unroll
                for (int ks = 0; ks < 2; ++ks) {
                    qh2[ks] = *(const bf16x8*)&lds[QH + rowc * 72 + ks * 32 + lg * 8];
                    ql2[ks] = *(const bf16x8*)&lds[QL + rowc * 72 + ks * 32 + lg * 8];
                }
                f32x4 c[5];
#pragma unroll
                for (int nt = 0; nt < 5; ++nt) {
                    f32x4 acc = {0,0,0,0};
                    int colr = nt * 16 + l15; if (colr > 65) colr = 65;
#pragma unroll
                    for (int ks = 0; ks < 2; ++ks) {
                        bf16x8 khf = *(const bf16x8*)&lds[KH + colr * 72 + ks * 32 + lg * 8];
                        bf16x8 klf = *(const bf16x8*)&lds[KL + colr * 72 + ks * 32 + lg * 8];
                        acc = __builtin_amdgcn_mfma_f32_16x16x32_bf16(qh2[ks], khf, acc, 0, 0, 0);
                        acc = __builtin_amdgcn_mfma_f32_16x16x32_bf16(qh2[ks], klf, acc, 0, 0, 0);
                        acc = __builtin_amdgcn_mfma_f32_16x16x32_bf16(ql2[ks], khf, acc, 0, 0, 0);
                    }
                    c[nt] = acc;
                }
#pragma unroll
                for (int r = 0; r < 4; ++r) {
                    int srow = mt * 16 + lg * 4 + r;
                    int fi = (srow >= 44) ? 2 : ((srow >= 22) ? 1 : 0);
                    float sv[5];
                    float mv = -INFINITY;
#pragma unroll
                    for (int nt = 0; nt < 5; ++nt) {
                        int j = nt * 16 + l15;
                        int fj = (j >= 44) ? 2 : ((j >= 22) ? 1 : 0);
                        float s = c[nt][r];
                        if ((fi == 0 && fj == 2) || (fi == 2 && fj == 0)) s = 0.f;
                        sv[nt] = s;
                        if (j < NS) mv = fmaxf(mv, s);
                    }
#pragma unroll
                    for (int off = 1; off < 16; off <<= 1) mv = fmaxf(mv, __shfl_xor(mv, off));
                    float thr = mv * (1.f / 9.f);
                    float ev[5];
                    float M2 = -INFINITY;
#pragma unroll
                    for (int nt = 0; nt < 5; ++nt) {
                        int j = nt * 16 + l15;
                        float e = (j < NS && fabsf(sv[nt]) > thr) ? sv[nt] : NEGV;
                        ev[nt] = e;
                        M2 = fmaxf(M2, e);
                    }
#pragma unroll
                    for (int off = 1; off < 16; off <<= 1) M2 = fmaxf(M2, __shfl_xor(M2, off));
                    float sum = 0.f;
#pragma unroll
                    for (int nt = 0; nt < 5; ++nt) {
                        float p = __expf(ev[nt] - M2);
                        pst[t][nt][r] = p;
                        sum += p;
                    }
#pragma unroll
                    for (int off = 1; off < 16; off <<= 1) sum += __shfl_xor(sum, off);
                    float inv = 1.f / sum;
#pragma unroll
                    for (int nt = 0; nt < 5; ++nt) pst[t][nt][r] *= inv;
                }
#pragma unroll
                for (int r = 0; r < 4; ++r) {
                    int srow = mt * 16 + lg * 4 + r;
                    if (srow < NS) {
#pragma unroll
                        for (int nt = 0; nt < 4; ++nt)
                            lds[QH + srow * 72 + nt * 16 + l15] = bfc(pst[t][nt][r]);
                        if (l15 < 2) lds[QH + srow * 72 + 64 + l15] = bfc(pst[t][4][r]);
                    }
                }
            }
        }
        __syncthreads();

#pragma unroll
        for (int t5 = 0; t5 < 5; ++t5) {
            int tile = wv * 5 + t5;
            int mt = tile >> 2, nt = tile & 3;
            int rowc = mt * 16 + l15; if (rowc > 65) rowc = 65;
            int dn = nt * 16 + l15;
            f32x4 acc = {0,0,0,0};
#pragma unroll
            for (int ks = 0; ks < 2; ++ks) {
                bf16x8 pa = *(const bf16x8*)&lds[QH + rowc * 72 + ks * 32 + lg * 8];
                bf16x8 vb = *(const bf16x8*)&lds[VT + dn * 72 + ks * 32 + lg * 8];
                acc = __builtin_amdgcn_mfma_f32_16x16x32_bf16(pa, vb, acc, 0, 0, 0);
            }
            float v64 = b2f(lds[VT + dn * 72 + 64]);
            float v65 = b2f(lds[VT + dn * 72 + 65]);
#pragma unroll
            for (int r = 0; r < 4; ++r) {
                int s2 = mt * 16 + lg * 4 + r;
                if (s2 < NS) {
                    float p64 = b2f(lds[QH + s2 * 72 + 64]);
                    float p65 = b2f(lds[QH + s2 * 72 + 65]);
                    OTf[dn * 76 + s2] = acc[r] + p64 * v64 + p65 * v65;
                }
            }
        }
        __syncthreads();

#pragma unroll
        for (int t = 0; t < 2; ++t) {
            f32x4 acc = {0,0,0,0};
#pragma unroll
            for (int ks = 0; ks < 2; ++ks) {
                f32x4 f0 = *(const f32x4*)&OTf[d * 76 + ks * 32 + lg * 8];
                f32x4 f1 = *(const f32x4*)&OTf[d * 76 + ks * 32 + lg * 8 + 4];
                bf16x8 bb;
#pragma unroll
                for (int i = 0; i < 4; ++i) {
                    bb[i]     = (short)bfc(f0[i]);
                    bb[i + 4] = (short)bfc(f1[i]);
                }
                acc = __builtin_amdgcn_mfma_f32_16x16x32_bf16(wfrag[t][ks], bb, acc, 0, 0, 0);
            }
            float o64 = OTf[d * 76 + 64];
            float o65 = OTf[d * 76 + 65];
#pragma unroll
            for (int r = 0; r < 4; ++r) {
                int jj = t * 16 + lg * 4 + r;
                if (jj < NJ) {
                    float res = acc[r] + Wcls[64 * NJ + jj] * o64
                                       + Wcls[65 * NJ + jj] * o65 + bcls[jj];
                    out[((b * (NW * NJ) + w * NJ + jj) * NHD) + h * 64 + wv * 16 + l15] = res;
                }
            }
        }
        __syncthreads();
    }
}

__global__ __launch_bounds__(256) void ft_ln_kernel(
    const float* __restrict__ Wft, const float* __restrict__ bft,
    const float* __restrict__ a2, const float* __restrict__ b2,
    float* __restrict__ out)
{
    __shared__ float sA[16 * NOUT];
    const int tid = threadIdx.x;
    const int base = blockIdx.x * (16 * NOUT);

    for (int idx = tid; idx < 16 * NOUT; idx += 256) sA[idx] = out[base + idx];
    __syncthreads();

    float a0[16], a1[16];
    const float bf0 = bft[tid], bf1 = bft[tid + 256];
#pragma unroll
    for (int r = 0; r < 16; ++r) { a0[r] = bf0; a1[r] = bf1; }

    for (int f = 0; f < NOUT; ++f) {
        float w0 = Wft[f * NOUT + tid];
        float w1 = Wft[f * NOUT + tid + 256];
#pragma unroll
        for (int r = 0; r < 16; ++r) {
            float a = sA[r * NOUT + f];
            a0[r] = fmaf(a, w0, a0[r]);
            a1[r] = fmaf(a, w1, a1[r]);
        }
    }
    __syncthreads();
#pragma unroll
    for (int r = 0; r < 16; ++r) {
        sA[r * NOUT + tid]       = fmaxf(a0[r], 0.f);
        sA[r * NOUT + tid + 256] = fmaxf(a1[r], 0.f);
    }
    __syncthreads();

    const int lane = tid & 63, wvv = tid >> 6;
    for (int r = wvv * 4; r < wvv * 4 + 4; ++r) {
        float s = 0.f, sq = 0.f;
        float vals[8];
#pragma unroll
        for (int u = 0; u < 8; ++u) {
            float y = sA[r * NOUT + u * 64 + lane];
            vals[u] = y;
            s += y;
            sq = fmaf(y, y, sq);
        }
#pragma unroll
        for (int off = 32; off; off >>= 1) {
            s  += __shfl_xor(s,  off);
            sq += __shfl_xor(sq, off);
        }
        float mean = s * (1.0f / 512.0f);
        float var  = fmaxf((sq - 512.0f * mean * mean) * (1.0f / 511.0f), 0.0f);
        float inv  = 1.0f / (sqrtf(var) + 1e-6f);
#pragma unroll
        for (int u = 0; u < 8; ++u) {
            int c = u * 64 + lane;
            out[base + r * NOUT + c] = a2[c] * (vals[u] - mean) * inv + b2[c];
        }
    }
}

extern "C" void kernel_launch(void* const* d_in, const int* in_sizes, int n_in,
                              void* d_out, int out_size, void* d_ws, size_t ws_size,
                              hipStream_t stream) {
    (void)in_sizes; (void)n_in; (void)out_size;
    const float* x    = (const float*)d_in[0];
    const float* Wq   = (const float*)d_in[1];
    const float* bq   = (const float*)d_in[2];
    const float* Wk   = (const float*)d_in[3];
    const float* bk   = (const float*)d_in[4];
    const float* Wv   = (const float*)d_in[5];
    const float* bv   = (const float*)d_in[6];
    const float* Wcls = (const float*)d_in[7];
    const float* bcls = (const float*)d_in[8];
    const float* Wft  = (const float*)d_in[9];
    const float* bft  = (const float*)d_in[10];
    const float* a2   = (const float*)d_in[11];
    const float* b2   = (const float*)d_in[12];
    float* out = (float*)d_out;

    if (ws_size >= (size_t)WS_NEED_BYTES) {
        unsigned short* ws = (unsigned short*)d_ws;
        prep_kernel<<<1792, 256, 0, stream>>>(Wq, Wk, Wv, Wft, ws);
        attn_kernel2<<<NB * NW * 2, 256, 0, stream>>>(x, bq, bk, bv, Wcls, bcls,
                                                      ws, out);
        ft_ln2<<<(NB * NW * NJ) / 16, 256, 0, stream>>>(ws, bft, a2, b2, out);
    } else {
        attn_kernel<<<NB * NW * 2, 256, 0, stream>>>(x, Wq, bq, Wk, bk, Wv, bv,
                                                     Wcls, bcls, out);
        ft_ln_kernel<<<(NB * NW * NJ) / 16, 256, 0, stream>>>(Wft, bft, a2, b2, out);
    }
}

// Round 5
// 338.050 us; speedup vs baseline: 7.1158x; 1.6108x over previous
//
#include <hip/hip_runtime.h>
#include <math.h>

#define NB 128
#define NT 8
#define NJ 22
#define NF 128
#define NH 8
#define NDH 64
#define NS 66     // 3*NJ
#define NW 6      // NT-2
#define NOUT 512
#define NHD 512   // NH*NDH
#define NEGV -9e15f
#define HPB 4
#define RTOT 22528   // B*T*J

typedef short bf16x8 __attribute__((ext_vector_type(8)));
typedef float f32x4  __attribute__((ext_vector_type(4)));

// ---- LDS regions for fallback attn kernels (ushort offsets) ----
#define XWPH 0
#define XWPL 8448
#define QH   16896
#define QL   21648
#define KH   26400
#define KL   31152
#define OTF_U 26400
#define VT   36128
#define LDS_USHORT 40736

// ---- workspace layout (ushort offsets) ----
#define WQH 0          // prepped W^T hi/lo: [512][128]
#define WQL 65536
#define WKH 131072
#define WKL 196608
#define WVT 262144
#define WFH 327680     // WftT hi [512][512]
#define WFL 589824
#define GQH 851968     // per-row q/k/v: [22528][512]
#define GQL 12386304
#define GKH 23920640
#define GKL 35454976
#define GV  46989312
#define WS_FULL_BYTES 117047296ULL
#define WS_MID_BYTES  1703936ULL

__device__ __forceinline__ unsigned short bfc(float f) {
    union { float f; unsigned u; } v; v.f = f;
    unsigned r = v.u + 0x7FFFu + ((v.u >> 16) & 1u);
    return (unsigned short)(r >> 16);
}
__device__ __forceinline__ float b2f(unsigned short h) {
    union { unsigned u; float f; } v; v.u = ((unsigned)h) << 16;
    return v.f;
}

// ---------------------------------------------------------------------------
// prep: transpose + bf16 hi/lo split of Wq/Wk/Wv/Wft into ws
// ---------------------------------------------------------------------------
__global__ __launch_bounds__(256) void prep_kernel(
    const float* __restrict__ Wq, const float* __restrict__ Wk,
    const float* __restrict__ Wv, const float* __restrict__ Wft,
    unsigned short* __restrict__ ws)
{
    int idx = blockIdx.x * 256 + threadIdx.x;
    if (idx < 196608) {
        int m = idx >> 16;
        int r = idx & 65535;
        int col = r >> 7, f = r & 127;
        const float* W = (m == 0) ? Wq : ((m == 1) ? Wk : Wv);
        float v = W[f * NHD + col];
        unsigned short h = bfc(v);
        if (m == 0)      { ws[WQH + r] = h; ws[WQL + r] = bfc(v - b2f(h)); }
        else if (m == 1) { ws[WKH + r] = h; ws[WKL + r] = bfc(v - b2f(h)); }
        else             { ws[WVT + r] = h; }
    } else {
        int r = idx - 196608;
        int col = r >> 9, f = r & 511;
        float v = Wft[f * NOUT + col];
        unsigned short h = bfc(v);
        ws[WFH + r] = h;
        ws[WFL + r] = bfc(v - b2f(h));
    }
}

// ---------------------------------------------------------------------------
// Phase 1: QKV projection GEMM over all (b,t,j) rows.
// grid (704, 3): M=32 rows/block, mat in grid.y. Writes q/k hi/lo + relu(v).
// ---------------------------------------------------------------------------
__global__ __launch_bounds__(256) void qkv_kernel(
    const float* __restrict__ x,
    const float* __restrict__ bq, const float* __restrict__ bk,
    const float* __restrict__ bv,
    const unsigned short* __restrict__ ws,
    unsigned short* __restrict__ wso)
{
    __shared__ __align__(16) unsigned short ah[32 * 136];
    __shared__ __align__(16) unsigned short al[32 * 136];
    const int tid = threadIdx.x, lane = tid & 63, wv = tid >> 6;
    const int l15 = lane & 15, lg = lane >> 4;
    const int mat = blockIdx.y;
    const int row0 = blockIdx.x * 32;

    const float cdiv = -0.0719557841560639f;
    for (int idx = tid; idx < 32 * 128; idx += 256) {
        int rr = idx >> 7, f = idx & 127;
        int r = row0 + rr;
        int b = r / 176;
        int tj = r - b * 176;
        int t = tj / 22, j = tj - t * 22;
        float xv = x[r * NF + f];
        float dv = __expf(cdiv * (float)(f & ~1));
        float pe = ((f & 1) == 0) ? (__sinf((float)j * dv) + __sinf((float)t * dv))
                                  : (__cosf((float)j * dv) + __cosf((float)t * dv));
        float val = xv + pe;
        unsigned short hs = bfc(val);
        ah[rr * 136 + f] = hs;
        al[rr * 136 + f] = bfc(val - b2f(hs));
    }
    __syncthreads();

    const unsigned short* WH = (mat == 0) ? (ws + WQH) : ((mat == 1) ? (ws + WKH) : (ws + WVT));
    const unsigned short* WL = (mat == 0) ? (ws + WQL) : (ws + WKL);
    const float* bias = (mat == 0) ? bq : ((mat == 1) ? bk : bv);
    unsigned short* OH = (mat == 0) ? (wso + GQH) : ((mat == 1) ? (wso + GKH) : (wso + GV));
    unsigned short* OL = (mat == 0) ? (wso + GQL) : (wso + GKL);

    f32x4 acc[2][8];
#pragma unroll
    for (int m = 0; m < 2; ++m)
#pragma unroll
        for (int g = 0; g < 8; ++g) acc[m][g] = (f32x4){0, 0, 0, 0};

#pragma unroll
    for (int ka = 0; ka < 4; ++ka) {
        bf16x8 afh[2], afl[2];
#pragma unroll
        for (int m = 0; m < 2; ++m) {
            afh[m] = *(const bf16x8*)&ah[(m * 16 + l15) * 136 + ka * 32 + lg * 8];
            afl[m] = *(const bf16x8*)&al[(m * 16 + l15) * 136 + ka * 32 + lg * 8];
        }
#pragma unroll
        for (int g = 0; g < 8; ++g) {
            int col = (wv * 8 + g) * 16 + l15;
            bf16x8 bh = *(const bf16x8*)&WH[col * 128 + ka * 32 + lg * 8];
#pragma unroll
            for (int m = 0; m < 2; ++m)
                acc[m][g] = __builtin_amdgcn_mfma_f32_16x16x32_bf16(afh[m], bh, acc[m][g], 0, 0, 0);
            if (mat < 2) {
                bf16x8 bl = *(const bf16x8*)&WL[col * 128 + ka * 32 + lg * 8];
#pragma unroll
                for (int m = 0; m < 2; ++m) {
                    acc[m][g] = __builtin_amdgcn_mfma_f32_16x16x32_bf16(afh[m], bl, acc[m][g], 0, 0, 0);
                    acc[m][g] = __builtin_amdgcn_mfma_f32_16x16x32_bf16(afl[m], bh, acc[m][g], 0, 0, 0);
                }
            }
        }
    }

#pragma unroll
    for (int g = 0; g < 8; ++g) {
        int col = (wv * 8 + g) * 16 + l15;
        float bv_ = bias[col];
#pragma unroll
        for (int m = 0; m < 2; ++m) {
#pragma unroll
            for (int r = 0; r < 4; ++r) {
                int row = row0 + m * 16 + lg * 4 + r;
                float v = acc[m][g][r] + bv_;
                if (mat == 0) {
                    v *= 0.125f;
                    unsigned short h = bfc(v);
                    OH[row * 512 + col] = h;
                    OL[row * 512 + col] = bfc(v - b2f(h));
                } else if (mat == 1) {
                    unsigned short h = bfc(v);
                    OH[row * 512 + col] = h;
                    OL[row * 512 + col] = bfc(v - b2f(h));
                } else {
                    OH[row * 512 + col] = bfc(fmaxf(v, 0.f));
                }
            }
        }
    }
}

// ---------------------------------------------------------------------------
// Phase 2: attention per (b,w,h). q/k fragments straight from global ws.
// LDS: P hi/lo [66][72], VT [64][72], OT fp32 [64][76]. 3 barriers.
// ---------------------------------------------------------------------------
#define P2_PH 0
#define P2_PL 4752
#define P2_VT 9504
#define P2_OT 14112
#define P2_TOT 23840

__global__ __launch_bounds__(256) void attn_kernel3(
    const unsigned short* __restrict__ ws,
    const float* __restrict__ Wcls, const float* __restrict__ bcls,
    float* __restrict__ out)
{
    __shared__ __align__(16) unsigned short lds[P2_TOT];
    float* OTf = (float*)&lds[P2_OT];

    const int tid  = threadIdx.x;
    const int lane = tid & 63;
    const int wv   = tid >> 6;
    const int l15  = lane & 15;
    const int lg   = lane >> 4;
    const int bid  = blockIdx.x;
    const int h = bid & 7;
    const int w = (bid >> 3) % NW;
    const int b = bid / (NW * NH);
    const int rowbase = b * 176 + w * 22;
    const int colh = h * 64;
    const int d = wv * 16 + l15;

    // Wcls A-fragments
    bf16x8 wfrag[2][2];
#pragma unroll
    for (int mt = 0; mt < 2; ++mt)
#pragma unroll
        for (int ks = 0; ks < 2; ++ks) {
            int j = mt * 16 + l15;
            bf16x8 t;
#pragma unroll
            for (int i = 0; i < 8; ++i) {
                int s = ks * 32 + lg * 8 + i;
                float v = (j < NJ) ? Wcls[s * NJ + j] : 0.f;
                t[i] = (short)bfc(v);
            }
            wfrag[mt][ks] = t;
        }

    // stage VT from global v
    for (int idx = tid; idx < 66 * 8; idx += 256) {
        int s = idx >> 3, dc = (idx & 7) * 8;
        bf16x8 vv = *(const bf16x8*)&ws[GV + (rowbase + s) * 512 + colh + dc];
#pragma unroll
        for (int i = 0; i < 8; ++i) lds[P2_VT + (dc + i) * 72 + s] = (unsigned short)vv[i];
    }

    // scores + mask + threshold + softmax -> P hi/lo
#pragma unroll
    for (int t = 0; t < 2; ++t) {
        const int mt = (t == 0) ? wv : 4;
        const bool act = (t == 0) || (wv == 0);
        if (act) {
            int rowc = mt * 16 + l15; if (rowc > 65) rowc = 65;
            bf16x8 qh2[2], ql2[2];
#pragma unroll
            for (int ks = 0; ks < 2; ++ks) {
                qh2[ks] = *(const bf16x8*)&ws[GQH + (rowbase + rowc) * 512 + colh + ks * 32 + lg * 8];
                ql2[ks] = *(const bf16x8*)&ws[GQL + (rowbase + rowc) * 512 + colh + ks * 32 + lg * 8];
            }
            f32x4 c[5];
#pragma unroll
            for (int nt = 0; nt < 5; ++nt) {
                f32x4 acc = {0, 0, 0, 0};
                int colr = nt * 16 + l15; if (colr > 65) colr = 65;
#pragma unroll
                for (int ks = 0; ks < 2; ++ks) {
                    bf16x8 khf = *(const bf16x8*)&ws[GKH + (rowbase + colr) * 512 + colh + ks * 32 + lg * 8];
                    bf16x8 klf = *(const bf16x8*)&ws[GKL + (rowbase + colr) * 512 + colh + ks * 32 + lg * 8];
                    acc = __builtin_amdgcn_mfma_f32_16x16x32_bf16(qh2[ks], khf, acc, 0, 0, 0);
                    acc = __builtin_amdgcn_mfma_f32_16x16x32_bf16(qh2[ks], klf, acc, 0, 0, 0);
                    acc = __builtin_amdgcn_mfma_f32_16x16x32_bf16(ql2[ks], khf, acc, 0, 0, 0);
                }
                c[nt] = acc;
            }
#pragma unroll
            for (int r = 0; r < 4; ++r) {
                int srow = mt * 16 + lg * 4 + r;
                int fi = (srow >= 44) ? 2 : ((srow >= 22) ? 1 : 0);
                float sv[5];
                float mv = -INFINITY;
#pragma unroll
                for (int nt = 0; nt < 5; ++nt) {
                    int j = nt * 16 + l15;
                    int fj = (j >= 44) ? 2 : ((j >= 22) ? 1 : 0);
                    float s = c[nt][r];
                    if ((fi == 0 && fj == 2) || (fi == 2 && fj == 0)) s = 0.f;
                    sv[nt] = s;
                    if (j < NS) mv = fmaxf(mv, s);
                }
#pragma unroll
                for (int off = 1; off < 16; off <<= 1) mv = fmaxf(mv, __shfl_xor(mv, off));
                float thr = mv * (1.f / 9.f);
                float ev[5];
                float M2 = -INFINITY;
#pragma unroll
                for (int nt = 0; nt < 5; ++nt) {
                    int j = nt * 16 + l15;
                    float e = (j < NS && fabsf(sv[nt]) > thr) ? sv[nt] : NEGV;
                    ev[nt] = e;
                    M2 = fmaxf(M2, e);
                }
#pragma unroll
                for (int off = 1; off < 16; off <<= 1) M2 = fmaxf(M2, __shfl_xor(M2, off));
                float pv5[5];
                float sum = 0.f;
#pragma unroll
                for (int nt = 0; nt < 5; ++nt) {
                    float p = __expf(ev[nt] - M2);
                    pv5[nt] = p;
                    sum += p;
                }
#pragma unroll
                for (int off = 1; off < 16; off <<= 1) sum += __shfl_xor(sum, off);
                float inv = 1.f / sum;
                if (srow < NS) {
#pragma unroll
                    for (int nt = 0; nt < 5; ++nt) {
                        float p = pv5[nt] * inv;
                        unsigned short ph = bfc(p);
                        unsigned short pl = bfc(p - b2f(ph));
                        if (nt < 4) {
                            lds[P2_PH + srow * 72 + nt * 16 + l15] = ph;
                            lds[P2_PL + srow * 72 + nt * 16 + l15] = pl;
                        } else if (l15 < 2) {
                            lds[P2_PH + srow * 72 + 64 + l15] = ph;
                            lds[P2_PL + srow * 72 + 64 + l15] = pl;
                        }
                    }
                }
            }
        }
    }
    __syncthreads();   // P + VT ready

    // PV -> OT (fp32), s=64,65 correction
#pragma unroll
    for (int t5 = 0; t5 < 5; ++t5) {
        int tile = wv * 5 + t5;
        int mt = tile >> 2, nt = tile & 3;
        int rowc = mt * 16 + l15; if (rowc > 65) rowc = 65;
        int dn = nt * 16 + l15;
        f32x4 acc = {0, 0, 0, 0};
#pragma unroll
        for (int ks = 0; ks < 2; ++ks) {
            bf16x8 pah = *(const bf16x8*)&lds[P2_PH + rowc * 72 + ks * 32 + lg * 8];
            bf16x8 pal = *(const bf16x8*)&lds[P2_PL + rowc * 72 + ks * 32 + lg * 8];
            bf16x8 vb  = *(const bf16x8*)&lds[P2_VT + dn * 72 + ks * 32 + lg * 8];
            acc = __builtin_amdgcn_mfma_f32_16x16x32_bf16(pah, vb, acc, 0, 0, 0);
            acc = __builtin_amdgcn_mfma_f32_16x16x32_bf16(pal, vb, acc, 0, 0, 0);
        }
        float v64 = b2f(lds[P2_VT + dn * 72 + 64]);
        float v65 = b2f(lds[P2_VT + dn * 72 + 65]);
#pragma unroll
        for (int r = 0; r < 4; ++r) {
            int s2 = mt * 16 + lg * 4 + r;
            if (s2 < NS) {
                float p64 = b2f(lds[P2_PH + s2 * 72 + 64]) + b2f(lds[P2_PL + s2 * 72 + 64]);
                float p65 = b2f(lds[P2_PH + s2 * 72 + 65]) + b2f(lds[P2_PL + s2 * 72 + 65]);
                OTf[dn * 76 + s2] = acc[r] + p64 * v64 + p65 * v65;
            }
        }
    }
    __syncthreads();   // OT ready

    // Wcls (OT hi/lo double-MFMA) + out
#pragma unroll
    for (int t = 0; t < 2; ++t) {
        f32x4 acc = {0, 0, 0, 0};
#pragma unroll
        for (int ks = 0; ks < 2; ++ks) {
            f32x4 f0 = *(const f32x4*)&OTf[d * 76 + ks * 32 + lg * 8];
            f32x4 f1 = *(const f32x4*)&OTf[d * 76 + ks * 32 + lg * 8 + 4];
            bf16x8 bh_, bl_;
#pragma unroll
            for (int i = 0; i < 4; ++i) {
                unsigned short h0 = bfc(f0[i]);
                bh_[i] = (short)h0; bl_[i] = (short)bfc(f0[i] - b2f(h0));
                unsigned short h1 = bfc(f1[i]);
                bh_[i + 4] = (short)h1; bl_[i + 4] = (short)bfc(f1[i] - b2f(h1));
            }
            acc = __builtin_amdgcn_mfma_f32_16x16x32_bf16(wfrag[t][ks], bh_, acc, 0, 0, 0);
            acc = __builtin_amdgcn_mfma_f32_16x16x32_bf16(wfrag[t][ks], bl_, acc, 0, 0, 0);
        }
        float o64 = OTf[d * 76 + 64];
        float o65 = OTf[d * 76 + 65];
#pragma unroll
        for (int r = 0; r < 4; ++r) {
            int jj = t * 16 + lg * 4 + r;
            if (jj < NJ) {
                float res = acc[r] + Wcls[64 * NJ + jj] * o64
                                   + Wcls[65 * NJ + jj] * o65 + bcls[jj];
                out[((b * (NW * NJ) + w * NJ + jj) * NHD) + h * 64 + wv * 16 + l15] = res;
            }
        }
    }
}

// ---------------------------------------------------------------------------
// ft v3: M=32/block, wave owns 2 msub x 8 nt (6 MFMA per B-frag pair).
// ---------------------------------------------------------------------------
__global__ __launch_bounds__(256) void ft_ln3(
    const unsigned short* __restrict__ ws,
    const float* __restrict__ bft,
    const float* __restrict__ a2, const float* __restrict__ b2,
    float* __restrict__ out)
{
    __shared__ __align__(16) unsigned short sAH[32 * 528];
    __shared__ __align__(16) unsigned short sAL[32 * 528];
    __shared__ float red[2][4][32];
    const int tid = threadIdx.x, lane = tid & 63, wv = tid >> 6;
    const int l15 = lane & 15, lg = lane >> 4;
    const int base = blockIdx.x * (32 * NOUT);

    for (int idx = tid; idx < 32 * NOUT; idx += 256) {
        int r = idx >> 9, c = idx & 511;
        float v = out[base + idx];
        unsigned short h = bfc(v);
        sAH[r * 528 + c] = h;
        sAL[r * 528 + c] = bfc(v - b2f(h));
    }
    __syncthreads();

    f32x4 acc[2][8];
#pragma unroll
    for (int m = 0; m < 2; ++m)
#pragma unroll
        for (int g = 0; g < 8; ++g) acc[m][g] = (f32x4){0, 0, 0, 0};

    for (int ka = 0; ka < 16; ++ka) {
        bf16x8 afh[2], afl[2];
#pragma unroll
        for (int m = 0; m < 2; ++m) {
            afh[m] = *(const bf16x8*)&sAH[(m * 16 + l15) * 528 + ka * 32 + lg * 8];
            afl[m] = *(const bf16x8*)&sAL[(m * 16 + l15) * 528 + ka * 32 + lg * 8];
        }
#pragma unroll
        for (int g = 0; g < 8; ++g) {
            int col = (wv * 8 + g) * 16 + l15;
            bf16x8 bh = *(const bf16x8*)&ws[WFH + col * 512 + ka * 32 + lg * 8];
            bf16x8 bl = *(const bf16x8*)&ws[WFL + col * 512 + ka * 32 + lg * 8];
#pragma unroll
            for (int m = 0; m < 2; ++m) {
                acc[m][g] = __builtin_amdgcn_mfma_f32_16x16x32_bf16(afh[m], bh, acc[m][g], 0, 0, 0);
                acc[m][g] = __builtin_amdgcn_mfma_f32_16x16x32_bf16(afh[m], bl, acc[m][g], 0, 0, 0);
                acc[m][g] = __builtin_amdgcn_mfma_f32_16x16x32_bf16(afl[m], bh, acc[m][g], 0, 0, 0);
            }
        }
    }

    // bias + relu
#pragma unroll
    for (int g = 0; g < 8; ++g) {
        int col = (wv * 8 + g) * 16 + l15;
        float bfv = bft[col];
#pragma unroll
        for (int m = 0; m < 2; ++m)
#pragma unroll
            for (int r = 0; r < 4; ++r)
                acc[m][g][r] = fmaxf(acc[m][g][r] + bfv, 0.f);
    }

    // per-row stats
    float ps[2][4], pq[2][4];
#pragma unroll
    for (int m = 0; m < 2; ++m)
#pragma unroll
        for (int r = 0; r < 4; ++r) {
            float s = 0.f, q = 0.f;
#pragma unroll
            for (int g = 0; g < 8; ++g) {
                s += acc[m][g][r];
                q = fmaf(acc[m][g][r], acc[m][g][r], q);
            }
            ps[m][r] = s; pq[m][r] = q;
        }
#pragma unroll
    for (int off = 1; off < 16; off <<= 1) {
#pragma unroll
        for (int m = 0; m < 2; ++m)
#pragma unroll
            for (int r = 0; r < 4; ++r) {
                ps[m][r] += __shfl_xor(ps[m][r], off);
                pq[m][r] += __shfl_xor(pq[m][r], off);
            }
    }
    if (l15 == 0) {
#pragma unroll
        for (int m = 0; m < 2; ++m)
#pragma unroll
            for (int r = 0; r < 4; ++r) {
                int row = m * 16 + lg * 4 + r;
                red[0][wv][row] = ps[m][r];
                red[1][wv][row] = pq[m][r];
            }
    }
    __syncthreads();

    float mean[2][4], inv[2][4];
#pragma unroll
    for (int m = 0; m < 2; ++m)
#pragma unroll
        for (int r = 0; r < 4; ++r) {
            int row = m * 16 + lg * 4 + r;
            float s = red[0][0][row] + red[0][1][row] + red[0][2][row] + red[0][3][row];
            float q = red[1][0][row] + red[1][1][row] + red[1][2][row] + red[1][3][row];
            float mn = s * (1.0f / 512.0f);
            float var = fmaxf((q - 512.0f * mn * mn) * (1.0f / 511.0f), 0.0f);
            mean[m][r] = mn;
            inv[m][r] = 1.0f / (sqrtf(var) + 1e-6f);
        }
#pragma unroll
    for (int g = 0; g < 8; ++g) {
        int col = (wv * 8 + g) * 16 + l15;
        float av2 = a2[col], bv2 = b2[col];
#pragma unroll
        for (int m = 0; m < 2; ++m)
#pragma unroll
            for (int r = 0; r < 4; ++r) {
                int row = m * 16 + lg * 4 + r;
                out[base + row * NOUT + col] = av2 * (acc[m][g][r] - mean[m][r]) * inv[m][r] + bv2;
            }
    }
}

// ===========================================================================
// Middle fallback (R4 attn, proven): used if WS_MID <= ws < WS_FULL
// ===========================================================================
__global__ __launch_bounds__(256) void attn_kernel2(
    const float* __restrict__ x,
    const float* __restrict__ bq, const float* __restrict__ bk,
    const float* __restrict__ bv,
    const float* __restrict__ Wcls, const float* __restrict__ bcls,
    const unsigned short* __restrict__ ws,
    float* __restrict__ out)
{
    __shared__ __align__(16) unsigned short lds[LDS_USHORT];
    float* OTf = (float*)&lds[OTF_U];

    const int tid  = threadIdx.x;
    const int lane = tid & 63;
    const int wv   = tid >> 6;
    const int l15  = lane & 15;
    const int lg   = lane >> 4;
    const int bid  = blockIdx.x;
    const int hb   = bid & 1;
    const int w    = (bid >> 1) % NW;
    const int b    = bid / (2 * NW);

    const float cdiv = -0.0719557841560639f;
    for (int idx = tid; idx < NS * NF; idx += 256) {
        int s = idx >> 7, f = idx & 127;
        int i = (s >= 44) ? 2 : ((s >= 22) ? 1 : 0);
        int j = s - i * NJ;
        int fr = w + i;
        float xv = x[((b * NT + fr) * NJ + j) * NF + f];
        float dv = __expf(cdiv * (float)(f & ~1));
        float pe = ((f & 1) == 0) ? (__sinf((float)j * dv) + __sinf((float)fr * dv))
                                  : (__cosf((float)j * dv) + __cosf((float)fr * dv));
        float val = xv + pe;
        unsigned short hs = bfc(val);
        int addr = s * 128 + ((((f >> 3) ^ (s & 15))) << 3) + (f & 7);
        lds[XWPH + addr] = hs;
        lds[XWPL + addr] = bfc(val - b2f(hs));
    }

    bf16x8 wfrag[2][2];
#pragma unroll
    for (int mt = 0; mt < 2; ++mt)
#pragma unroll
        for (int ks = 0; ks < 2; ++ks) {
            int j = mt * 16 + l15;
            bf16x8 t;
#pragma unroll
            for (int i = 0; i < 8; ++i) {
                int s = ks * 32 + lg * 8 + i;
                float v = (j < NJ) ? Wcls[s * NJ + j] : 0.f;
                t[i] = (short)bfc(v);
            }
            wfrag[mt][ks] = t;
        }
    __syncthreads();

    for (int hh = 0; hh < HPB; ++hh) {
        const int h = hb * HPB + hh;
        const int colg = h * 64 + wv * 16 + l15;
        const int d    = wv * 16 + l15;

        bf16x8 qbh[4], qbl[4], kbh[4], kbl[4], vbh[4];
#pragma unroll
        for (int ks = 0; ks < 4; ++ks) {
            int o = colg * 128 + ks * 32 + lg * 8;
            qbh[ks] = *(const bf16x8*)&ws[WQH + o];
            qbl[ks] = *(const bf16x8*)&ws[WQL + o];
            kbh[ks] = *(const bf16x8*)&ws[WKH + o];
            kbl[ks] = *(const bf16x8*)&ws[WKL + o];
            vbh[ks] = *(const bf16x8*)&ws[WVT + o];
        }
        const float bqv = bq[colg], bkv = bk[colg], bvv = bv[colg];

        f32x4 aq[5], ak[5], av[5];
#pragma unroll
        for (int mt = 0; mt < 5; ++mt) {
            aq[mt] = (f32x4){0,0,0,0}; ak[mt] = (f32x4){0,0,0,0}; av[mt] = (f32x4){0,0,0,0};
        }
#pragma unroll
        for (int ks = 0; ks < 4; ++ks) {
#pragma unroll
            for (int mt = 0; mt < 5; ++mt) {
                int rowc = mt * 16 + l15; if (rowc > 65) rowc = 65;
                int sw = rowc * 128 + (((ks * 4 + lg) ^ (rowc & 15)) << 3);
                bf16x8 ah = *(const bf16x8*)&lds[XWPH + sw];
                bf16x8 al = *(const bf16x8*)&lds[XWPL + sw];
                aq[mt] = __builtin_amdgcn_mfma_f32_16x16x32_bf16(ah, qbh[ks], aq[mt], 0, 0, 0);
                aq[mt] = __builtin_amdgcn_mfma_f32_16x16x32_bf16(ah, qbl[ks], aq[mt], 0, 0, 0);
                aq[mt] = __builtin_amdgcn_mfma_f32_16x16x32_bf16(al, qbh[ks], aq[mt], 0, 0, 0);
                ak[mt] = __builtin_amdgcn_mfma_f32_16x16x32_bf16(ah, kbh[ks], ak[mt], 0, 0, 0);
                ak[mt] = __builtin_amdgcn_mfma_f32_16x16x32_bf16(ah, kbl[ks], ak[mt], 0, 0, 0);
                ak[mt] = __builtin_amdgcn_mfma_f32_16x16x32_bf16(al, kbh[ks], ak[mt], 0, 0, 0);
                av[mt] = __builtin_amdgcn_mfma_f32_16x16x32_bf16(ah, vbh[ks], av[mt], 0, 0, 0);
            }
        }
#pragma unroll
        for (int mt = 0; mt < 5; ++mt) {
#pragma unroll
            for (int r = 0; r < 4; ++r) {
                int s = mt * 16 + lg * 4 + r;
                if (s < NS) {
                    float qv = (aq[mt][r] + bqv) * 0.125f;
                    unsigned short qh_ = bfc(qv);
                    lds[QH + s * 72 + d] = qh_;
                    lds[QL + s * 72 + d] = bfc(qv - b2f(qh_));
                    float kv = ak[mt][r] + bkv;
                    unsigned short kh2 = bfc(kv);
                    lds[KH + s * 72 + d] = kh2;
                    lds[KL + s * 72 + d] = bfc(kv - b2f(kh2));
                    lds[VT + d * 72 + s] = bfc(fmaxf(av[mt][r] + bvv, 0.f));
                }
            }
        }
        __syncthreads();

#pragma unroll
        for (int t = 0; t < 2; ++t) {
            const int mt = (t == 0) ? wv : 4;
            const bool act = (t == 0) || (wv == 0);
            if (act) {
                int rowc = mt * 16 + l15; if (rowc > 65) rowc = 65;
                bf16x8 qh2[2], ql2[2];
#pragma unroll
                for (int ks = 0; ks < 2; ++ks) {
                    qh2[ks] = *(const bf16x8*)&lds[QH + rowc * 72 + ks * 32 + lg * 8];
                    ql2[ks] = *(const bf16x8*)&lds[QL + rowc * 72 + ks * 32 + lg * 8];
                }
                f32x4 c[5];
#pragma unroll
                for (int nt = 0; nt < 5; ++nt) {
                    f32x4 acc = {0,0,0,0};
                    int colr = nt * 16 + l15; if (colr > 65) colr = 65;
#pragma unroll
                    for (int ks = 0; ks < 2; ++ks) {
                        bf16x8 khf = *(const bf16x8*)&lds[KH + colr * 72 + ks * 32 + lg * 8];
                        bf16x8 klf = *(const bf16x8*)&lds[KL + colr * 72 + ks * 32 + lg * 8];
                        acc = __builtin_amdgcn_mfma_f32_16x16x32_bf16(qh2[ks], khf, acc, 0, 0, 0);
                        acc = __builtin_amdgcn_mfma_f32_16x16x32_bf16(qh2[ks], klf, acc, 0, 0, 0);
                        acc = __builtin_amdgcn_mfma_f32_16x16x32_bf16(ql2[ks], khf, acc, 0, 0, 0);
                    }
                    c[nt] = acc;
                }
#pragma unroll
                for (int r = 0; r < 4; ++r) {
                    int srow = mt * 16 + lg * 4 + r;
                    int fi = (srow >= 44) ? 2 : ((srow >= 22) ? 1 : 0);
                    float sv[5];
                    float mv = -INFINITY;
#pragma unroll
                    for (int nt = 0; nt < 5; ++nt) {
                        int j = nt * 16 + l15;
                        int fj = (j >= 44) ? 2 : ((j >= 22) ? 1 : 0);
                        float s = c[nt][r];
                        if ((fi == 0 && fj == 2) || (fi == 2 && fj == 0)) s = 0.f;
                        sv[nt] = s;
                        if (j < NS) mv = fmaxf(mv, s);
                    }
#pragma unroll
                    for (int off = 1; off < 16; off <<= 1) mv = fmaxf(mv, __shfl_xor(mv, off));
                    float thr = mv * (1.f / 9.f);
                    float ev[5];
                    float M2 = -INFINITY;
#pragma unroll
                    for (int nt = 0; nt < 5; ++nt) {
                        int j = nt * 16 + l15;
                        float e = (j < NS && fabsf(sv[nt]) > thr) ? sv[nt] : NEGV;
                        ev[nt] = e;
                        M2 = fmaxf(M2, e);
                    }
#pragma unroll
                    for (int off = 1; off < 16; off <<= 1) M2 = fmaxf(M2, __shfl_xor(M2, off));
                    float pv5[5];
                    float sum = 0.f;
#pragma unroll
                    for (int nt = 0; nt < 5; ++nt) {
                        float p = __expf(ev[nt] - M2);
                        pv5[nt] = p;
                        sum += p;
                    }
#pragma unroll
                    for (int off = 1; off < 16; off <<= 1) sum += __shfl_xor(sum, off);
                    float inv = 1.f / sum;
                    if (srow < NS) {
#pragma unroll
                        for (int nt = 0; nt < 5; ++nt) {
                            float p = pv5[nt] * inv;
                            unsigned short ph = bfc(p);
                            unsigned short pl = bfc(p - b2f(ph));
                            if (nt < 4) {
                                lds[QH + srow * 72 + nt * 16 + l15] = ph;
                                lds[QL + srow * 72 + nt * 16 + l15] = pl;
                            } else if (l15 < 2) {
                                lds[QH + srow * 72 + 64 + l15] = ph;
                                lds[QL + srow * 72 + 64 + l15] = pl;
                            }
                        }
                    }
                }
            }
        }
        __syncthreads();

#pragma unroll
        for (int t5 = 0; t5 < 5; ++t5) {
            int tile = wv * 5 + t5;
            int mt = tile >> 2, nt = tile & 3;
            int rowc = mt * 16 + l15; if (rowc > 65) rowc = 65;
            int dn = nt * 16 + l15;
            f32x4 acc = {0,0,0,0};
#pragma unroll
            for (int ks = 0; ks < 2; ++ks) {
                bf16x8 pah = *(const bf16x8*)&lds[QH + rowc * 72 + ks * 32 + lg * 8];
                bf16x8 pal = *(const bf16x8*)&lds[QL + rowc * 72 + ks * 32 + lg * 8];
                bf16x8 vb  = *(const bf16x8*)&lds[VT + dn * 72 + ks * 32 + lg * 8];
                acc = __builtin_amdgcn_mfma_f32_16x16x32_bf16(pah, vb, acc, 0, 0, 0);
                acc = __builtin_amdgcn_mfma_f32_16x16x32_bf16(pal, vb, acc, 0, 0, 0);
            }
            float v64 = b2f(lds[VT + dn * 72 + 64]);
            float v65 = b2f(lds[VT + dn * 72 + 65]);
#pragma unroll
            for (int r = 0; r < 4; ++r) {
                int s2 = mt * 16 + lg * 4 + r;
                if (s2 < NS) {
                    float p64 = b2f(lds[QH + s2 * 72 + 64]) + b2f(lds[QL + s2 * 72 + 64]);
                    float p65 = b2f(lds[QH + s2 * 72 + 65]) + b2f(lds[QL + s2 * 72 + 65]);
                    OTf[dn * 76 + s2] = acc[r] + p64 * v64 + p65 * v65;
                }
            }
        }
        __syncthreads();

#pragma unroll
        for (int t = 0; t < 2; ++t) {
            f32x4 acc = {0,0,0,0};
#pragma unroll
            for (int ks = 0; ks < 2; ++ks) {
                f32x4 f0 = *(const f32x4*)&OTf[d * 76 + ks * 32 + lg * 8];
                f32x4 f1 = *(const f32x4*)&OTf[d * 76 + ks * 32 + lg * 8 + 4];
                bf16x8 bh_, bl_;
#pragma unroll
                for (int i = 0; i < 4; ++i) {
                    unsigned short h0 = bfc(f0[i]);
                    bh_[i] = (short)h0; bl_[i] = (short)bfc(f0[i] - b2f(h0));
                    unsigned short h1 = bfc(f1[i]);
                    bh_[i + 4] = (short)h1; bl_[i + 4] = (short)bfc(f1[i] - b2f(h1));
                }
                acc = __builtin_amdgcn_mfma_f32_16x16x32_bf16(wfrag[t][ks], bh_, acc, 0, 0, 0);
                acc = __builtin_amdgcn_mfma_f32_16x16x32_bf16(wfrag[t][ks], bl_, acc, 0, 0, 0);
            }
            float o64 = OTf[d * 76 + 64];
            float o65 = OTf[d * 76 + 65];
#pragma unroll
            for (int r = 0; r < 4; ++r) {
                int jj = t * 16 + lg * 4 + r;
                if (jj < NJ) {
                    float res = acc[r] + Wcls[64 * NJ + jj] * o64
                                       + Wcls[65 * NJ + jj] * o65 + bcls[jj];
                    out[((b * (NW * NJ) + w * NJ + jj) * NHD) + h * 64 + wv * 16 + l15] = res;
                }
            }
        }
        __syncthreads();
    }
}

// ===========================================================================
// Ultra fallback (no ws): R3-style fp32-weight attn + fp32 ft/LN
// ===========================================================================
__global__ __launch_bounds__(256) void attn_kernel(
    const float* __restrict__ x,
    const float* __restrict__ Wq, const float* __restrict__ bq,
    const float* __restrict__ Wk, const float* __restrict__ bk,
    const float* __restrict__ Wv, const float* __restrict__ bv,
    const float* __restrict__ Wcls, const float* __restrict__ bcls,
    float* __restrict__ out)
{
    __shared__ __align__(16) unsigned short lds[LDS_USHORT];
    float* OTf = (float*)&lds[OTF_U];

    const int tid  = threadIdx.x;
    const int lane = tid & 63;
    const int wv   = tid >> 6;
    const int l15  = lane & 15;
    const int lg   = lane >> 4;
    const int bid  = blockIdx.x;
    const int hb   = bid & 1;
    const int w    = (bid >> 1) % NW;
    const int b    = bid / (2 * NW);

    const float cdiv = -0.0719557841560639f;
    for (int idx = tid; idx < NS * NF; idx += 256) {
        int s = idx >> 7, f = idx & 127;
        int i = (s >= 44) ? 2 : ((s >= 22) ? 1 : 0);
        int j = s - i * NJ;
        int fr = w + i;
        float xv = x[((b * NT + fr) * NJ + j) * NF + f];
        float dv = __expf(cdiv * (float)(f & ~1));
        float pe = ((f & 1) == 0) ? (__sinf((float)j * dv) + __sinf((float)fr * dv))
                                  : (__cosf((float)j * dv) + __cosf((float)fr * dv));
        float val = xv + pe;
        unsigned short hs = bfc(val);
        int addr = s * 128 + ((((f >> 3) ^ (s & 15))) << 3) + (f & 7);
        lds[XWPH + addr] = hs;
        lds[XWPL + addr] = bfc(val - b2f(hs));
    }

    bf16x8 wfrag[2][2];
#pragma unroll
    for (int mt = 0; mt < 2; ++mt)
#pragma unroll
        for (int ks = 0; ks < 2; ++ks) {
            int j = mt * 16 + l15;
            bf16x8 t;
#pragma unroll
            for (int i = 0; i < 8; ++i) {
                int s = ks * 32 + lg * 8 + i;
                float v = (j < NJ) ? Wcls[s * NJ + j] : 0.f;
                t[i] = (short)bfc(v);
            }
            wfrag[mt][ks] = t;
        }
    __syncthreads();

    for (int hh = 0; hh < HPB; ++hh) {
        const int h = hb * HPB + hh;
        const int colg = h * 64 + wv * 16 + l15;
        const int d    = wv * 16 + l15;

        bf16x8 qbh[4], qbl[4], kbh[4], kbl[4], vbh[4];
#pragma unroll
        for (int ks = 0; ks < 4; ++ks) {
            bf16x8 th, tl, kh_, kl_, vh_;
#pragma unroll
            for (int i = 0; i < 8; ++i) {
                int f = ks * 32 + lg * 8 + i;
                float wq = Wq[f * NHD + colg];
                unsigned short hq = bfc(wq);
                th[i] = (short)hq; tl[i] = (short)bfc(wq - b2f(hq));
                float wk = Wk[f * NHD + colg];
                unsigned short hk = bfc(wk);
                kh_[i] = (short)hk; kl_[i] = (short)bfc(wk - b2f(hk));
                vh_[i] = (short)bfc(Wv[f * NHD + colg]);
            }
            qbh[ks] = th; qbl[ks] = tl; kbh[ks] = kh_; kbl[ks] = kl_; vbh[ks] = vh_;
        }
        const float bqv = bq[colg], bkv = bk[colg], bvv = bv[colg];

        for (int mt = 0; mt < 5; ++mt) {
            f32x4 aq = {0,0,0,0}, ak = {0,0,0,0}, av = {0,0,0,0};
            int rowc = mt * 16 + l15; if (rowc > 65) rowc = 65;
#pragma unroll
            for (int ks = 0; ks < 4; ++ks) {
                int sw = rowc * 128 + (((ks * 4 + lg) ^ (rowc & 15)) << 3);
                bf16x8 ah = *(const bf16x8*)&lds[XWPH + sw];
                bf16x8 al = *(const bf16x8*)&lds[XWPL + sw];
                aq = __builtin_amdgcn_mfma_f32_16x16x32_bf16(ah, qbh[ks], aq, 0, 0, 0);
                aq = __builtin_amdgcn_mfma_f32_16x16x32_bf16(ah, qbl[ks], aq, 0, 0, 0);
                aq = __builtin_amdgcn_mfma_f32_16x16x32_bf16(al, qbh[ks], aq, 0, 0, 0);
                ak = __builtin_amdgcn_mfma_f32_16x16x32_bf16(ah, kbh[ks], ak, 0, 0, 0);
                ak = __builtin_amdgcn_mfma_f32_16x16x32_bf16(ah, kbl[ks], ak, 0, 0, 0);
                ak = __builtin_amdgcn_mfma_f32_16x16x32_bf16(al, kbh[ks], ak, 0, 0, 0);
                av = __builtin_amdgcn_mfma_f32_16x16x32_bf16(ah, vbh[ks], av, 0, 0, 0);
            }
#pragma unroll
            for (int r = 0; r < 4; ++r) {
                int s = mt * 16 + lg * 4 + r;
                if (s < NS) {
                    float qv = (aq[r] + bqv) * 0.125f;
                    unsigned short qh_ = bfc(qv);
                    lds[QH + s * 72 + d] = qh_;
                    lds[QL + s * 72 + d] = bfc(qv - b2f(qh_));
                    float kv = ak[r] + bkv;
                    unsigned short kh2 = bfc(kv);
                    lds[KH + s * 72 + d] = kh2;
                    lds[KL + s * 72 + d] = bfc(kv - b2f(kh2));
                    lds[VT + d * 72 + s] = bfc(fmaxf(av[r] + bvv, 0.f));
                }
            }
        }
        __syncthreads();

        float pst[2][5][4];
#pragma unroll
        for (int t = 0; t < 2; ++t) {
            const int mt = (t == 0) ? wv : 4;
            const bool act = (t == 0) || (wv == 0);
            if (act) {
                int rowc = mt * 16 + l15; if (rowc > 65) rowc = 65;
                bf16x8 qh2[2], ql2[2];
#pragma unroll
                for (int ks = 0; ks < 2; ++ks) {
                    qh2[ks] = *(const bf16x8*)&lds[QH + rowc * 72 + ks * 32 + lg * 8];
                    ql2[ks] = *(const bf16x8*)&lds[QL + rowc * 72 + ks * 32 + lg * 8];
                }
                f32x4 c[5];
#pragma unroll
                for (int nt = 0; nt < 5; ++nt) {
                    f32x4 acc = {0,0,0,0};
                    int colr = nt * 16 + l15; if (colr > 65) colr = 65;
#pragma unroll
                    for (int ks = 0; ks < 2; ++ks) {
                        bf16x8 khf = *(const bf16x8*)&lds[KH + colr * 72 + ks * 32 + lg * 8];
                        bf16x8 klf = *(const bf16x8*)&lds[KL + colr * 72 + ks * 32 + lg * 8];
                        acc = __builtin_amdgcn_mfma_f32_16x16x32_bf16(qh2[ks], khf, acc, 0, 0, 0);
                        acc = __builtin_amdgcn_mfma_f32_16x16x32_bf16(qh2[ks], klf, acc, 0, 0, 0);
                        acc = __builtin_amdgcn_mfma_f32_16x16x32_bf16(ql2[ks], khf, acc, 0, 0, 0);
                    }
                    c[nt] = acc;
                }
#pragma unroll
                for (int r = 0; r < 4; ++r) {
                    int srow = mt * 16 + lg * 4 + r;
                    int fi = (srow >= 44) ? 2 : ((srow >= 22) ? 1 : 0);
                    float sv[5];
                    float mv = -INFINITY;
#pragma unroll
                    for (int nt = 0; nt < 5; ++nt) {
                        int j = nt * 16 + l15;
                        int fj = (j >= 44) ? 2 : ((j >= 22) ? 1 : 0);
                        float s = c[nt][r];
                        if ((fi == 0 && fj == 2) || (fi == 2 && fj == 0)) s = 0.f;
                        sv[nt] = s;
                        if (j < NS) mv = fmaxf(mv, s);
                    }
#pragma unroll
                    for (int off = 1; off < 16; off <<= 1) mv = fmaxf(mv, __shfl_xor(mv, off));
                    float thr = mv * (1.f / 9.f);
                    float ev[5];
                    float M2 = -INFINITY;
#pragma unroll
                    for (int nt = 0; nt < 5; ++nt) {
                        int j = nt * 16 + l15;
                        float e = (j < NS && fabsf(sv[nt]) > thr) ? sv[nt] : NEGV;
                        ev[nt] = e;
                        M2 = fmaxf(M2, e);
                    }
#pragma unroll
                    for (int off = 1; off < 16; off <<= 1) M2 = fmaxf(M2, __shfl_xor(M2, off));
                    float sum = 0.f;
#pragma unroll
                    for (int nt = 0; nt < 5; ++nt) {
                        float p = __expf(ev[nt] - M2);
                        pst[t][nt][r] = p;
                        sum += p;
                    }
#pragma unroll
                    for (int off = 1; off < 16; off <<= 1) sum += __shfl_xor(sum, off);
                    float inv = 1.f / sum;
#pragma unroll
                    for (int nt = 0; nt < 5; ++nt) pst[t][nt][r] *= inv;
                }
#pragma unroll
                for (int r = 0; r < 4; ++r) {
                    int srow = mt * 16 + lg * 4 + r;
                    if (srow < NS) {
#pragma unroll
                        for (int nt = 0; nt < 4; ++nt)
                            lds[QH + srow * 72 + nt * 16 + l15] = bfc(pst[t][nt][r]);
                        if (l15 < 2) lds[QH + srow * 72 + 64 + l15] = bfc(pst[t][4][r]);
                    }
                }
            }
        }
        __syncthreads();

#pragma unroll
        for (int t5 = 0; t5 < 5; ++t5) {
            int tile = wv * 5 + t5;
            int mt = tile >> 2, nt = tile & 3;
            int rowc = mt * 16 + l15; if (rowc > 65) rowc = 65;
            int dn = nt * 16 + l15;
            f32x4 acc = {0,0,0,0};
#pragma unroll
            for (int ks = 0; ks < 2; ++ks) {
                bf16x8 pa = *(const bf16x8*)&lds[QH + rowc * 72 + ks * 32 + lg * 8];
                bf16x8 vb = *(const bf16x8*)&lds[VT + dn * 72 + ks * 32 + lg * 8];
                acc = __builtin_amdgcn_mfma_f32_16x16x32_bf16(pa, vb, acc, 0, 0, 0);
            }
            float v64 = b2f(lds[VT + dn * 72 + 64]);
            float v65 = b2f(lds[VT + dn * 72 + 65]);
#pragma unroll
            for (int r = 0; r < 4; ++r) {
                int s2 = mt * 16 + lg * 4 + r;
                if (s2 < NS) {
                    float p64 = b2f(lds[QH + s2 * 72 + 64]);
                    float p65 = b2f(lds[QH + s2 * 72 + 65]);
                    OTf[dn * 76 + s2] = acc[r] + p64 * v64 + p65 * v65;
                }
            }
        }
        __syncthreads();

#pragma unroll
        for (int t = 0; t < 2; ++t) {
            f32x4 acc = {0,0,0,0};
#pragma unroll
            for (int ks = 0; ks < 2; ++ks) {
                f32x4 f0 = *(const f32x4*)&OTf[d * 76 + ks * 32 + lg * 8];
                f32x4 f1 = *(const f32x4*)&OTf[d * 76 + ks * 32 + lg * 8 + 4];
                bf16x8 bb;
#pragma unroll
                for (int i = 0; i < 4; ++i) {
                    bb[i]     = (short)bfc(f0[i]);
                    bb[i + 4] = (short)bfc(f1[i]);
                }
                acc = __builtin_amdgcn_mfma_f32_16x16x32_bf16(wfrag[t][ks], bb, acc, 0, 0, 0);
            }
            float o64 = OTf[d * 76 + 64];
            float o65 = OTf[d * 76 + 65];
#pragma unroll
            for (int r = 0; r < 4; ++r) {
                int jj = t * 16 + lg * 4 + r;
                if (jj < NJ) {
                    float res = acc[r] + Wcls[64 * NJ + jj] * o64
                                       + Wcls[65 * NJ + jj] * o65 + bcls[jj];
                    out[((b * (NW * NJ) + w * NJ + jj) * NHD) + h * 64 + wv * 16 + l15] = res;
                }
            }
        }
        __syncthreads();
    }
}

__global__ __launch_bounds__(256) void ft_ln_kernel(
    const float* __restrict__ Wft, const float* __restrict__ bft,
    const float* __restrict__ a2, const float* __restrict__ b2,
    float* __restrict__ out)
{
    __shared__ float sA[16 * NOUT];
    const int tid = threadIdx.x;
    const int base = blockIdx.x * (16 * NOUT);

    for (int idx = tid; idx < 16 * NOUT; idx += 256) sA[idx] = out[base + idx];
    __syncthreads();

    float a0[16], a1[16];
    const float bf0 = bft[tid], bf1 = bft[tid + 256];
#pragma unroll
    for (int r = 0; r < 16; ++r) { a0[r] = bf0; a1[r] = bf1; }

    for (int f = 0; f < NOUT; ++f) {
        float w0 = Wft[f * NOUT + tid];
        float w1 = Wft[f * NOUT + tid + 256];
#pragma unroll
        for (int r = 0; r < 16; ++r) {
            float a = sA[r * NOUT + f];
            a0[r] = fmaf(a, w0, a0[r]);
            a1[r] = fmaf(a, w1, a1[r]);
        }
    }
    __syncthreads();
#pragma unroll
    for (int r = 0; r < 16; ++r) {
        sA[r * NOUT + tid]       = fmaxf(a0[r], 0.f);
        sA[r * NOUT + tid + 256] = fmaxf(a1[r], 0.f);
    }
    __syncthreads();

    const int lane = tid & 63, wvv = tid >> 6;
    for (int r = wvv * 4; r < wvv * 4 + 4; ++r) {
        float s = 0.f, sq = 0.f;
        float vals[8];
#pragma unroll
        for (int u = 0; u < 8; ++u) {
            float y = sA[r * NOUT + u * 64 + lane];
            vals[u] = y;
            s += y;
            sq = fmaf(y, y, sq);
        }
#pragma unroll
        for (int off = 32; off; off >>= 1) {
            s  += __shfl_xor(s,  off);
            sq += __shfl_xor(sq, off);
        }
        float mean = s * (1.0f / 512.0f);
        float var  = fmaxf((sq - 512.0f * mean * mean) * (1.0f / 511.0f), 0.0f);
        float inv  = 1.0f / (sqrtf(var) + 1e-6f);
#pragma unroll
        for (int u = 0; u < 8; ++u) {
            int c = u * 64 + lane;
            out[base + r * NOUT + c] = a2[c] * (vals[u] - mean) * inv + b2[c];
        }
    }
}

extern "C" void kernel_launch(void* const* d_in, const int* in_sizes, int n_in,
                              void* d_out, int out_size, void* d_ws, size_t ws_size,
                              hipStream_t stream) {
    (void)in_sizes; (void)n_in; (void)out_size;
    const float* x    = (const float*)d_in[0];
    const float* Wq   = (const float*)d_in[1];
    const float* bq   = (const float*)d_in[2];
    const float* Wk   = (const float*)d_in[3];
    const float* bk   = (const float*)d_in[4];
    const float* Wv   = (const float*)d_in[5];
    const float* bv   = (const float*)d_in[6];
    const float* Wcls = (const float*)d_in[7];
    const float* bcls = (const float*)d_in[8];
    const float* Wft  = (const float*)d_in[9];
    const float* bft  = (const float*)d_in[10];
    const float* a2   = (const float*)d_in[11];
    const float* b2   = (const float*)d_in[12];
    float* out = (float*)d_out;

    if (ws_size >= WS_FULL_BYTES) {
        unsigned short* ws = (unsigned short*)d_ws;
        prep_kernel<<<1792, 256, 0, stream>>>(Wq, Wk, Wv, Wft, ws);
        qkv_kernel<<<dim3(704, 3), 256, 0, stream>>>(x, bq, bk, bv, ws, ws);
        attn_kernel3<<<NB * NW * NH, 256, 0, stream>>>(ws, Wcls, bcls, out);
        ft_ln3<<<528, 256, 0, stream>>>(ws, bft, a2, b2, out);
    } else if (ws_size >= WS_MID_BYTES) {
        unsigned short* ws = (unsigned short*)d_ws;
        prep_kernel<<<1792, 256, 0, stream>>>(Wq, Wk, Wv, Wft, ws);
        attn_kernel2<<<NB * NW * 2, 256, 0, stream>>>(x, bq, bk, bv, Wcls, bcls,
                                                      ws, out);
        ft_ln3<<<528, 256, 0, stream>>>(ws, bft, a2, b2, out);
    } else {
        attn_kernel<<<NB * NW * 2, 256, 0, stream>>>(x, Wq, bq, Wk, bk, Wv, bv,
                                                     Wcls, bcls, out);
        ft_ln_kernel<<<(NB * NW * NJ) / 16, 256, 0, stream>>>(Wft, bft, a2, b2, out);
    }
}